// Round 2
// baseline (238.847 us; speedup 1.0000x reference)
//
#include <hip/hip_runtime.h>
#include <hip/hip_bf16.h>

// BahdanauAttention on MI355X (gfx950). ALL float I/O is fp32 (per reference).
// Internal compute uses bf16 MFMA (no fp32 MFMA on CDNA4).
// Pipeline:
//  K0: cast fp32 -> bf16 (RNE) for query/enc/W_s/W_h/W_out into ws
//  K1: wsq = (2*log2e) * (query @ W_s^T)   fp32 -> ws        [MFMA bf16]
//  K1: whe = (2*log2e) * (enc   @ W_h^T)   fp32 -> ws        [MFMA bf16]
//  K3: energies via tanh(x)=1-2/(1+exp2(c*x)) (Sum v*1 dropped: softmax
//      shift-invariant), mask by src_lengths, softmax, context -> bf16 ws
//  K4: out = tanh([ctx|query] @ W_out^T) -> fp32 d_out       [MFMA bf16]

typedef __attribute__((ext_vector_type(8))) short bf16x8;
typedef __attribute__((ext_vector_type(4))) float floatx4;

#define C2LOG2E 2.8853900817779268f   // 2*log2(e)
#define LOG2E   1.4426950408889634f
#define NEGBIG  -1e30f

__device__ __forceinline__ float fexp2(float x) { return __builtin_amdgcn_exp2f(x); }
__device__ __forceinline__ float frcp(float x)  { return __builtin_amdgcn_rcpf(x); }

__device__ __forceinline__ unsigned int f2bf_bits(float f) {
    unsigned int u = __float_as_uint(f);
    return (u + 0x7fffu + ((u >> 16) & 1u)) >> 16;   // RNE (inputs finite)
}

// ---- K0: cast fp32 -> bf16, 4 elems/thread, segment by blockIdx -------------
__global__ __launch_bounds__(256) void cast_all_bf16(
    const float* __restrict__ q,  const float* __restrict__ e,
    const float* __restrict__ Ws, const float* __restrict__ Wh,
    const float* __restrict__ Wo,
    unsigned short* __restrict__ qb,  unsigned short* __restrict__ eb,
    unsigned short* __restrict__ Wsb, unsigned short* __restrict__ Whb,
    unsigned short* __restrict__ Wob)
{
    int blk = blockIdx.x;
    const float* src; unsigned short* dst; int base;
    if      (blk < 1024) { src = q;  dst = qb;  base = blk; }
    else if (blk < 2048) { src = e;  dst = eb;  base = blk - 1024; }
    else if (blk < 2304) { src = Ws; dst = Wsb; base = blk - 2048; }
    else if (blk < 2560) { src = Wh; dst = Whb; base = blk - 2304; }
    else                 { src = Wo; dst = Wob; base = blk - 2560; }
    size_t i = (size_t)base * 1024 + threadIdx.x * 4;
    float4 f = *(const float4*)(src + i);
    ushort4 o;
    o.x = (unsigned short)f2bf_bits(f.x);
    o.y = (unsigned short)f2bf_bits(f.y);
    o.z = (unsigned short)f2bf_bits(f.z);
    o.w = (unsigned short)f2bf_bits(f.w);
    *(ushort4*)(dst + i) = o;
}

// C[m][n] = scale * sum_k X[m][k] * W[n][k];  X:2048x512 bf16, W:512x512 bf16, C fp32
__global__ __launch_bounds__(256) void gemm_scale_f32(
    const unsigned short* __restrict__ X, const unsigned short* __restrict__ W,
    float* __restrict__ C, float scale)
{
    const int K = 512, N = 512;
    int tid  = threadIdx.x;
    int lane = tid & 63;
    int gw   = blockIdx.x * 4 + (tid >> 6);
    int nt   = gw & 31;          // N/16 = 32 tiles
    int mt   = gw >> 5;          // M/16 = 128 tiles
    int r    = lane & 15;
    int kq   = (lane >> 4) * 8;  // A[m=lane&15][k=quad*8+j]
    const bf16x8* xp = (const bf16x8*)(X + (size_t)(mt * 16 + r) * K + kq);
    const bf16x8* wp = (const bf16x8*)(W + (size_t)(nt * 16 + r) * K + kq);
    floatx4 acc = {0.f, 0.f, 0.f, 0.f};
#pragma unroll
    for (int k = 0; k < 16; ++k)
        acc = __builtin_amdgcn_mfma_f32_16x16x32_bf16(xp[k * 4], wp[k * 4], acc, 0, 0, 0);
    int row0 = (lane >> 4) * 4;  // C/D: col=lane&15, row=quad*4+reg (m89-verified)
    float* cp = C + (size_t)(mt * 16 + row0) * N + nt * 16 + r;
#pragma unroll
    for (int i = 0; i < 4; ++i) cp[i * N] = scale * acc[i];
}

// energies + masked softmax + context. Grid: 8 b * 32 ttiles = 256 blocks, 512 thr.
// Wave w (of 8) owns t-row (ttile*8 + w); lane owns s = lane + 64*j, j<4.
#define HC 32
__global__ __launch_bounds__(512) void attn_softmax_ctx(
    const float* __restrict__ Aq,          // 2048x512 scaled Ws_q
    const float* __restrict__ Bh,          // 2048x512 scaled Wh_e
    const float* __restrict__ Enc,         // fp32 8x256x512
    const float* __restrict__ Vv,          // fp32 512
    const int* __restrict__ Len,
    unsigned short* __restrict__ Ctx)      // bf16 2048x512 (internal)
{
    __shared__ float sB[256][HC + 1];
    __shared__ float sA[8][HC];
    __shared__ float sV[512];
    __shared__ float sW[8][256];

    const int H = 512;
    int tid   = threadIdx.x;
    int lane  = tid & 63;
    int w     = tid >> 6;                 // 0..7
    int b     = blockIdx.x >> 5;
    int ttile = blockIdx.x & 31;
    int row0g = b * 256 + ttile * 8;      // global (b*T+t) row base
    int len   = Len[b];
    int jmax  = (len + 63) >> 6;          // skip fully-masked 64-wide s blocks

    sV[tid] = -2.0f * Vv[tid];

    float acc[4] = {0.f, 0.f, 0.f, 0.f};

    for (int hc = 0; hc < H; hc += HC) {
        __syncthreads();
        {   // stage Wh_e' chunk: 256 rows x HC, 16 floats per thread
            int row = tid >> 1;
            int cb  = (tid & 1) * 16;
            const float* src = Bh + (size_t)(b * 256 + row) * H + hc + cb;
            float4 f0 = ((const float4*)src)[0];
            float4 f1 = ((const float4*)src)[1];
            float4 f2 = ((const float4*)src)[2];
            float4 f3 = ((const float4*)src)[3];
            float* dst = &sB[row][cb];
            dst[0]=f0.x;  dst[1]=f0.y;  dst[2]=f0.z;  dst[3]=f0.w;
            dst[4]=f1.x;  dst[5]=f1.y;  dst[6]=f1.z;  dst[7]=f1.w;
            dst[8]=f2.x;  dst[9]=f2.y;  dst[10]=f2.z; dst[11]=f2.w;
            dst[12]=f3.x; dst[13]=f3.y; dst[14]=f3.z; dst[15]=f3.w;
        }
        if (tid < 256) {                  // stage Ws_q' chunk: 8 rows x HC
            int row = tid >> 5, col = tid & 31;
            sA[row][col] = Aq[(size_t)(row0g + row) * H + hc + col];
        }
        __syncthreads();

        float av[HC], vv[HC];
#pragma unroll
        for (int hh = 0; hh < HC; ++hh) { av[hh] = sA[w][hh]; vv[hh] = sV[hc + hh]; }
#pragma unroll
        for (int j = 0; j < 4; ++j) {
            if (j < jmax) {               // uniform per-block branch
                int s = lane + 64 * j;
#pragma unroll
                for (int hh = 0; hh < HC; ++hh) {
                    float e = fexp2(av[hh] + sB[s][hh]);
                    acc[j] += vv[hh] * frcp(1.0f + e);
                }
            }
        }
    }

    // mask + softmax (full row resident in wave); finite sentinel, no infs
    float ev[4];
#pragma unroll
    for (int j = 0; j < 4; ++j) {
        int s = lane + 64 * j;
        ev[j] = (s < len) ? acc[j] : NEGBIG;
    }
    float m = fmaxf(fmaxf(ev[0], ev[1]), fmaxf(ev[2], ev[3]));
#pragma unroll
    for (int o = 1; o < 64; o <<= 1) m = fmaxf(m, __shfl_xor(m, o, 64));
    float wv[4];
    float wsum = 0.f;
#pragma unroll
    for (int j = 0; j < 4; ++j) { wv[j] = fexp2((ev[j] - m) * LOG2E); wsum += wv[j]; }
#pragma unroll
    for (int o = 1; o < 64; o <<= 1) wsum += __shfl_xor(wsum, o, 64);
    float inv = frcp(wsum);
#pragma unroll
    for (int j = 0; j < 4; ++j) sW[w][lane + 64 * j] = wv[j] * inv;
    // no sync: each wave reads only its own sW row below

    // context[t][h] = sum_s w[s]*enc[b][s][h]; lane owns 8 h (fp32 enc)
    float c0=0,c1=0,c2=0,c3=0,c4=0,c5=0,c6=0,c7=0;
    int h0 = lane * 8;
    const float* encb = Enc + (size_t)b * 256 * H + h0;
    for (int s = 0; s < len; ++s) {       // weights are exactly 0 beyond len
        float wt = sW[w][s];
        float4 u0 = ((const float4*)(encb + (size_t)s * H))[0];
        float4 u1 = ((const float4*)(encb + (size_t)s * H))[1];
        c0 += wt * u0.x;  c1 += wt * u0.y;  c2 += wt * u0.z;  c3 += wt * u0.w;
        c4 += wt * u1.x;  c5 += wt * u1.y;  c6 += wt * u1.z;  c7 += wt * u1.w;
    }
    unsigned short* outp = Ctx + (size_t)(row0g + w) * H + h0;
    uint4 o;
    o.x = f2bf_bits(c0) | (f2bf_bits(c1) << 16);
    o.y = f2bf_bits(c2) | (f2bf_bits(c3) << 16);
    o.z = f2bf_bits(c4) | (f2bf_bits(c5) << 16);
    o.w = f2bf_bits(c6) | (f2bf_bits(c7) << 16);
    *(uint4*)outp = o;
}

// out[m][n] = tanh( sum_{k<512} ctx[m][k]*Wout[n][k] + sum_{k<512} q[m][k]*Wout[n][512+k] )
__global__ __launch_bounds__(256) void out_gemm_tanh(
    const unsigned short* __restrict__ Ctx, const unsigned short* __restrict__ Q,
    const unsigned short* __restrict__ Wout, float* __restrict__ Out)
{
    const int K = 512, N = 512, KW = 1024;
    int tid  = threadIdx.x;
    int lane = tid & 63;
    int gw   = blockIdx.x * 4 + (tid >> 6);
    int nt   = gw & 31;
    int mt   = gw >> 5;
    int r    = lane & 15;
    int kq   = (lane >> 4) * 8;
    const bf16x8* cp  = (const bf16x8*)(Ctx  + (size_t)(mt * 16 + r) * K + kq);
    const bf16x8* qp  = (const bf16x8*)(Q    + (size_t)(mt * 16 + r) * K + kq);
    const bf16x8* wp  = (const bf16x8*)(Wout + (size_t)(nt * 16 + r) * KW + kq);
    const bf16x8* wp2 = (const bf16x8*)(Wout + (size_t)(nt * 16 + r) * KW + 512 + kq);
    floatx4 acc = {0.f, 0.f, 0.f, 0.f};
#pragma unroll
    for (int k = 0; k < 16; ++k)
        acc = __builtin_amdgcn_mfma_f32_16x16x32_bf16(cp[k * 4], wp[k * 4], acc, 0, 0, 0);
#pragma unroll
    for (int k = 0; k < 16; ++k)
        acc = __builtin_amdgcn_mfma_f32_16x16x32_bf16(qp[k * 4], wp2[k * 4], acc, 0, 0, 0);
    int row0 = (lane >> 4) * 4;
    float* op = Out + (size_t)(mt * 16 + row0) * N + nt * 16 + r;
#pragma unroll
    for (int i = 0; i < 4; ++i) {
        float t = 1.0f - 2.0f * frcp(1.0f + fexp2(C2LOG2E * acc[i]));
        op[i * N] = t;
    }
}

extern "C" void kernel_launch(void* const* d_in, const int* in_sizes, int n_in,
                              void* d_out, int out_size, void* d_ws, size_t ws_size,
                              hipStream_t stream)
{
    const float* query = (const float*)d_in[0]; // fp32 8x256x512
    const float* enc   = (const float*)d_in[1]; // fp32 8x256x512
    const int*   len   = (const int*)d_in[2];   // int32 8
    const float* Ws    = (const float*)d_in[3]; // fp32 512x512
    const float* Wh    = (const float*)d_in[4]; // fp32 512x512
    const float* v     = (const float*)d_in[5]; // fp32 512
    const float* Wout  = (const float*)d_in[6]; // fp32 512x1024
    float* out = (float*)d_out;                 // fp32 8x256x512

    float* wsq = (float*)d_ws;                           // 4 MiB
    float* whe = wsq + 2048 * 512;                       // 4 MiB
    unsigned short* ctx = (unsigned short*)(whe + 2048 * 512); // 2 MiB bf16
    unsigned short* qb  = ctx + 2048 * 512;              // 2 MiB bf16
    unsigned short* eb  = qb  + 2048 * 512;              // 2 MiB bf16
    unsigned short* Wsb = eb  + 2048 * 512;              // 0.5 MiB
    unsigned short* Whb = Wsb + 512 * 512;               // 0.5 MiB
    unsigned short* Wob = Whb + 512 * 512;               // 1 MiB

    cast_all_bf16<<<3072, 256, 0, stream>>>(query, enc, Ws, Wh, Wout,
                                            qb, eb, Wsb, Whb, Wob);
    gemm_scale_f32<<<1024, 256, 0, stream>>>(qb, Wsb, wsq, C2LOG2E);
    gemm_scale_f32<<<1024, 256, 0, stream>>>(eb, Whb, whe, C2LOG2E);
    attn_softmax_ctx<<<256, 512, 0, stream>>>(wsq, whe, enc, v, len, ctx);
    out_gemm_tanh<<<1024, 256, 0, stream>>>(ctx, qb, Wob, out);
}

// Round 3
// 216.675 us; speedup vs baseline: 1.1023x; 1.1023x over previous
//
#include <hip/hip_runtime.h>
#include <hip/hip_bf16.h>

// BahdanauAttention on MI355X (gfx950). ALL float I/O is fp32.
// Internal compute uses bf16 MFMA (no fp32 MFMA on CDNA4).
// Pipeline:
//  K0: cast fp32 -> bf16 (RNE) for query/enc/W_s/W_h/W_out into ws
//  K1: wsq = c*(query @ W_s^T), whe = c*(enc @ W_h^T)  [merged, MFMA bf16]
//  K2: zero E
//  K3: energies partial over h-quads -> atomicAdd fp32 E[2048][256]
//      tanh(x)=1-2/(1+exp2(c*x)); Sum v*1 dropped (softmax shift-invariant)
//  K4: softmax(E masked by len) + context -> bf16 ctx   [hq-split, 1024 blk]
//  K5: out = tanh([ctx|query] @ W_out^T) -> fp32 d_out  [MFMA bf16]

typedef __attribute__((ext_vector_type(8))) short bf16x8;
typedef __attribute__((ext_vector_type(4))) float floatx4;

#define C2LOG2E 2.8853900817779268f   // 2*log2(e)
#define LOG2E   1.4426950408889634f
#define NEGBIG  -1e30f

__device__ __forceinline__ float fexp2(float x) { return __builtin_amdgcn_exp2f(x); }
__device__ __forceinline__ float frcp(float x)  { return __builtin_amdgcn_rcpf(x); }

__device__ __forceinline__ unsigned int f2bf_bits(float f) {
    unsigned int u = __float_as_uint(f);
    return (u + 0x7fffu + ((u >> 16) & 1u)) >> 16;   // RNE (inputs finite)
}

// ---- K0: cast fp32 -> bf16, 4 elems/thread, segment by blockIdx -------------
__global__ __launch_bounds__(256) void cast_all_bf16(
    const float* __restrict__ q,  const float* __restrict__ e,
    const float* __restrict__ Ws, const float* __restrict__ Wh,
    const float* __restrict__ Wo,
    unsigned short* __restrict__ qb,  unsigned short* __restrict__ eb,
    unsigned short* __restrict__ Wsb, unsigned short* __restrict__ Whb,
    unsigned short* __restrict__ Wob)
{
    int blk = blockIdx.x;
    const float* src; unsigned short* dst; int base;
    if      (blk < 1024) { src = q;  dst = qb;  base = blk; }
    else if (blk < 2048) { src = e;  dst = eb;  base = blk - 1024; }
    else if (blk < 2304) { src = Ws; dst = Wsb; base = blk - 2048; }
    else if (blk < 2560) { src = Wh; dst = Whb; base = blk - 2304; }
    else                 { src = Wo; dst = Wob; base = blk - 2560; }
    size_t i = (size_t)base * 1024 + threadIdx.x * 4;
    float4 f = *(const float4*)(src + i);
    ushort4 o;
    o.x = (unsigned short)f2bf_bits(f.x);
    o.y = (unsigned short)f2bf_bits(f.y);
    o.z = (unsigned short)f2bf_bits(f.z);
    o.w = (unsigned short)f2bf_bits(f.w);
    *(ushort4*)(dst + i) = o;
}

// ---- K1: both staging GEMMs in one launch. grid 2048 ------------------------
// C[m][n] = scale * sum_k X[m][k] * W[n][k];  X:2048x512 bf16, W:512x512 bf16
__global__ __launch_bounds__(256) void gemm_scale_f32_2(
    const unsigned short* __restrict__ X1, const unsigned short* __restrict__ W1,
    float* __restrict__ C1,
    const unsigned short* __restrict__ X2, const unsigned short* __restrict__ W2,
    float* __restrict__ C2, float scale)
{
    const int K = 512, N = 512;
    int blk = blockIdx.x;
    const unsigned short* X; const unsigned short* W; float* C;
    if (blk < 1024) { X = X1; W = W1; C = C1; }
    else            { X = X2; W = W2; C = C2; blk -= 1024; }
    int tid  = threadIdx.x;
    int lane = tid & 63;
    int gw   = blk * 4 + (tid >> 6);
    int nt   = gw & 31;          // N/16 = 32 tiles
    int mt   = gw >> 5;          // M/16 = 128 tiles
    int r    = lane & 15;
    int kq   = (lane >> 4) * 8;  // A[m=lane&15][k=quad*8+j]
    const bf16x8* xp = (const bf16x8*)(X + (size_t)(mt * 16 + r) * K + kq);
    const bf16x8* wp = (const bf16x8*)(W + (size_t)(nt * 16 + r) * K + kq);
    floatx4 acc = {0.f, 0.f, 0.f, 0.f};
#pragma unroll
    for (int k = 0; k < 16; ++k)
        acc = __builtin_amdgcn_mfma_f32_16x16x32_bf16(xp[k * 4], wp[k * 4], acc, 0, 0, 0);
    int row0 = (lane >> 4) * 4;  // C/D: col=lane&15, row=quad*4+reg
    float* cp = C + (size_t)(mt * 16 + row0) * N + nt * 16 + r;
#pragma unroll
    for (int i = 0; i < 4; ++i) cp[i * N] = scale * acc[i];
}

// ---- K2: zero E (2 MB). 512 blocks x 256 thr x 1 float4 ---------------------
__global__ __launch_bounds__(256) void zero_E(float* __restrict__ E)
{
    size_t i = ((size_t)blockIdx.x * 256 + threadIdx.x) * 4;
    *(float4*)(E + i) = float4{0.f, 0.f, 0.f, 0.f};
}

// ---- K3: partial energies. grid 8b x 32ttile x 4hq = 1024 blocks, 512 thr ---
// Wave w owns t-row (ttile*8+w); lane owns s = lane+64j, j<jmax; h in quad.
#define HC 32
__global__ __launch_bounds__(512) void energies_partial(
    const float* __restrict__ Aq,          // 2048x512 scaled Ws_q
    const float* __restrict__ Bh,          // 2048x512 scaled Wh_e
    const float* __restrict__ Vv,          // fp32 512
    const int* __restrict__ Len,
    float* __restrict__ E)                 // fp32 2048x256, pre-zeroed
{
    __shared__ float sB[256][HC + 1];
    __shared__ float sA[8][HC];
    __shared__ float sV[128];

    const int H = 512;
    int tid   = threadIdx.x;
    int lane  = tid & 63;
    int w     = tid >> 6;                 // 0..7
    int b     = blockIdx.x >> 7;          // /128
    int ttile = (blockIdx.x >> 2) & 31;
    int hq    = blockIdx.x & 3;
    int row0g = b * 256 + ttile * 8;      // global (b*T+t) row base
    int len   = Len[b];
    int jmax  = (len + 63) >> 6;

    if (tid < 128) sV[tid] = -2.0f * Vv[hq * 128 + tid];

    float acc[4] = {0.f, 0.f, 0.f, 0.f};

    for (int hc = 0; hc < 128; hc += HC) {
        __syncthreads();
        {   // stage Wh_e' chunk: 256 rows x HC
            int row = tid >> 1;
            int cb  = (tid & 1) * 16;
            const float* src = Bh + (size_t)(b * 256 + row) * H + hq * 128 + hc + cb;
            float4 f0 = ((const float4*)src)[0];
            float4 f1 = ((const float4*)src)[1];
            float4 f2 = ((const float4*)src)[2];
            float4 f3 = ((const float4*)src)[3];
            float* dst = &sB[row][cb];
            dst[0]=f0.x;  dst[1]=f0.y;  dst[2]=f0.z;  dst[3]=f0.w;
            dst[4]=f1.x;  dst[5]=f1.y;  dst[6]=f1.z;  dst[7]=f1.w;
            dst[8]=f2.x;  dst[9]=f2.y;  dst[10]=f2.z; dst[11]=f2.w;
            dst[12]=f3.x; dst[13]=f3.y; dst[14]=f3.z; dst[15]=f3.w;
        }
        if (tid < 256) {                  // stage Ws_q' chunk: 8 rows x HC
            int row = tid >> 5, col = tid & 31;
            sA[row][col] = Aq[(size_t)(row0g + row) * H + hq * 128 + hc + col];
        }
        __syncthreads();

#pragma unroll
        for (int j = 0; j < 4; ++j) {
            if (j < jmax) {               // uniform per-block branch
                int s = lane + 64 * j;
#pragma unroll
                for (int hh = 0; hh < HC; ++hh) {
                    float e = fexp2(sA[w][hh] + sB[s][hh]);
                    acc[j] += sV[hc + hh] * frcp(1.0f + e);
                }
            }
        }
    }

    float* erow = E + (size_t)(row0g + w) * 256;
#pragma unroll
    for (int j = 0; j < 4; ++j)
        if (j < jmax) atomicAdd(erow + 64 * j + lane, acc[j]);
}

// ---- K4: softmax + context. grid 8b x 32ttile x 4hq = 1024 blocks, 512 thr --
// Wave w owns t-row; lane owns 2 h within the quad; full s-row in regs.
__global__ __launch_bounds__(512) void softmax_ctx(
    const float* __restrict__ E,           // fp32 2048x256
    const float* __restrict__ Enc,         // fp32 8x256x512
    const int* __restrict__ Len,
    unsigned short* __restrict__ Ctx)      // bf16 2048x512
{
    __shared__ float sW[8][256];
    const int H = 512;
    int tid   = threadIdx.x;
    int lane  = tid & 63;
    int w     = tid >> 6;
    int b     = blockIdx.x >> 7;
    int ttile = (blockIdx.x >> 2) & 31;
    int hq    = blockIdx.x & 3;
    int row0g = b * 256 + ttile * 8;
    int len   = Len[b];

    const float* erow = E + (size_t)(row0g + w) * 256;
    float ev[4];
#pragma unroll
    for (int j = 0; j < 4; ++j) {
        int s = lane + 64 * j;
        ev[j] = (s < len) ? erow[s] : NEGBIG;
    }
    float m = fmaxf(fmaxf(ev[0], ev[1]), fmaxf(ev[2], ev[3]));
#pragma unroll
    for (int o = 1; o < 64; o <<= 1) m = fmaxf(m, __shfl_xor(m, o, 64));
    float wv[4];
    float wsum = 0.f;
#pragma unroll
    for (int j = 0; j < 4; ++j) { wv[j] = fexp2((ev[j] - m) * LOG2E); wsum += wv[j]; }
#pragma unroll
    for (int o = 1; o < 64; o <<= 1) wsum += __shfl_xor(wsum, o, 64);
    float inv = frcp(wsum);
#pragma unroll
    for (int j = 0; j < 4; ++j) sW[w][lane + 64 * j] = wv[j] * inv;
    // no sync: each wave reads only its own sW row

    // context for h in [hq*128, hq*128+128): lane owns 2 h
    int h0 = hq * 128 + lane * 2;
    const float* encb = Enc + (size_t)b * 256 * H + h0;
    float c0 = 0.f, c1 = 0.f;
    for (int s = 0; s < len; ++s) {        // weights exactly 0 beyond len
        float wt = sW[w][s];
        float2 u = *(const float2*)(encb + (size_t)s * H);
        c0 += wt * u.x;  c1 += wt * u.y;
    }
    unsigned int o = f2bf_bits(c0) | (f2bf_bits(c1) << 16);
    *(unsigned int*)(Ctx + (size_t)(row0g + w) * H + h0) = o;
}

// ---- K5: out = tanh([ctx|q] @ Wout^T) ---------------------------------------
__global__ __launch_bounds__(256) void out_gemm_tanh(
    const unsigned short* __restrict__ Ctx, const unsigned short* __restrict__ Q,
    const unsigned short* __restrict__ Wout, float* __restrict__ Out)
{
    const int K = 512, N = 512, KW = 1024;
    int tid  = threadIdx.x;
    int lane = tid & 63;
    int gw   = blockIdx.x * 4 + (tid >> 6);
    int nt   = gw & 31;
    int mt   = gw >> 5;
    int r    = lane & 15;
    int kq   = (lane >> 4) * 8;
    const bf16x8* cp  = (const bf16x8*)(Ctx  + (size_t)(mt * 16 + r) * K + kq);
    const bf16x8* qp  = (const bf16x8*)(Q    + (size_t)(mt * 16 + r) * K + kq);
    const bf16x8* wp  = (const bf16x8*)(Wout + (size_t)(nt * 16 + r) * KW + kq);
    const bf16x8* wp2 = (const bf16x8*)(Wout + (size_t)(nt * 16 + r) * KW + 512 + kq);
    floatx4 acc = {0.f, 0.f, 0.f, 0.f};
#pragma unroll
    for (int k = 0; k < 16; ++k)
        acc = __builtin_amdgcn_mfma_f32_16x16x32_bf16(cp[k * 4], wp[k * 4], acc, 0, 0, 0);
#pragma unroll
    for (int k = 0; k < 16; ++k)
        acc = __builtin_amdgcn_mfma_f32_16x16x32_bf16(qp[k * 4], wp2[k * 4], acc, 0, 0, 0);
    int row0 = (lane >> 4) * 4;
    float* op = Out + (size_t)(mt * 16 + row0) * N + nt * 16 + r;
#pragma unroll
    for (int i = 0; i < 4; ++i) {
        float t = 1.0f - 2.0f * frcp(1.0f + fexp2(C2LOG2E * acc[i]));
        op[i * N] = t;
    }
}

extern "C" void kernel_launch(void* const* d_in, const int* in_sizes, int n_in,
                              void* d_out, int out_size, void* d_ws, size_t ws_size,
                              hipStream_t stream)
{
    const float* query = (const float*)d_in[0]; // fp32 8x256x512
    const float* enc   = (const float*)d_in[1]; // fp32 8x256x512
    const int*   len   = (const int*)d_in[2];   // int32 8
    const float* Ws    = (const float*)d_in[3]; // fp32 512x512
    const float* Wh    = (const float*)d_in[4]; // fp32 512x512
    const float* v     = (const float*)d_in[5]; // fp32 512
    const float* Wout  = (const float*)d_in[6]; // fp32 512x1024
    float* out = (float*)d_out;                 // fp32 8x256x512

    float* wsq = (float*)d_ws;                                  // 4 MiB
    float* whe = wsq + 2048 * 512;                              // 4 MiB
    unsigned short* ctx = (unsigned short*)(whe + 2048 * 512);  // 2 MiB bf16
    unsigned short* qb  = ctx + 2048 * 512;                     // 2 MiB bf16
    unsigned short* eb  = qb  + 2048 * 512;                     // 2 MiB bf16
    unsigned short* Wsb = eb  + 2048 * 512;                     // 0.5 MiB
    unsigned short* Whb = Wsb + 512 * 512;                      // 0.5 MiB
    unsigned short* Wob = Whb + 512 * 512;                      // 1 MiB
    float* E = (float*)eb;   // 2 MiB, aliases eb (dead after K1); zeroed by K2

    cast_all_bf16<<<3072, 256, 0, stream>>>(query, enc, Ws, Wh, Wout,
                                            qb, eb, Wsb, Whb, Wob);
    gemm_scale_f32_2<<<2048, 256, 0, stream>>>(qb, Wsb, wsq, eb, Whb, whe, C2LOG2E);
    zero_E<<<512, 256, 0, stream>>>(E);
    energies_partial<<<1024, 512, 0, stream>>>(wsq, whe, v, len, E);
    softmax_ctx<<<1024, 512, 0, stream>>>(E, enc, len, ctx);
    out_gemm_tanh<<<1024, 256, 0, stream>>>(ctx, qb, Wob, out);
}

// Round 4
// 197.551 us; speedup vs baseline: 1.2090x; 1.0968x over previous
//
#include <hip/hip_runtime.h>
#include <hip/hip_bf16.h>

// BahdanauAttention on MI355X (gfx950). ALL float I/O is fp32.
// Internal compute uses bf16 MFMA (no fp32 MFMA on CDNA4).
// Pipeline:
//  K0: cast fp32 -> bf16 (RNE) for query/enc/W_s/W_h/W_out into ws
//  K1: wsq = c*(query @ W_s^T), whe = c*(enc @ W_h^T)  [merged, MFMA bf16]
//  K2: zero E
//  K3: energies partial (hq x sq split) -> atomicAdd fp32 E[2048][256]
//      tanh(x)=1-2/(1+exp2(c*x)); Sum v*1 dropped (softmax shift-invariant)
//  K4a: softmax(E masked by len) -> bf16 weights Wb[2048][256]
//  K4b: ctx = Wb @ enc  [MFMA bf16, EncT via in-LDS transpose]
//  K5: out = tanh([ctx|query] @ W_out^T) -> fp32 d_out  [MFMA bf16]
// ws aliases: E/ctx share [8,10) MB (sequenced); Wb over Wsb/Whb (dead after K1).

typedef __attribute__((ext_vector_type(8))) short bf16x8;
typedef __attribute__((ext_vector_type(4))) float floatx4;

#define C2LOG2E 2.8853900817779268f   // 2*log2(e)
#define LOG2E   1.4426950408889634f
#define NEGBIG  -1e30f

__device__ __forceinline__ float fexp2(float x) { return __builtin_amdgcn_exp2f(x); }
__device__ __forceinline__ float frcp(float x)  { return __builtin_amdgcn_rcpf(x); }

__device__ __forceinline__ unsigned int f2bf_bits(float f) {
    unsigned int u = __float_as_uint(f);
    return (u + 0x7fffu + ((u >> 16) & 1u)) >> 16;   // RNE (inputs finite)
}

// ---- K0: cast fp32 -> bf16, 4 elems/thread, segment by blockIdx -------------
__global__ __launch_bounds__(256) void cast_all_bf16(
    const float* __restrict__ q,  const float* __restrict__ e,
    const float* __restrict__ Ws, const float* __restrict__ Wh,
    const float* __restrict__ Wo,
    unsigned short* __restrict__ qb,  unsigned short* __restrict__ eb,
    unsigned short* __restrict__ Wsb, unsigned short* __restrict__ Whb,
    unsigned short* __restrict__ Wob)
{
    int blk = blockIdx.x;
    const float* src; unsigned short* dst; int base;
    if      (blk < 1024) { src = q;  dst = qb;  base = blk; }
    else if (blk < 2048) { src = e;  dst = eb;  base = blk - 1024; }
    else if (blk < 2304) { src = Ws; dst = Wsb; base = blk - 2048; }
    else if (blk < 2560) { src = Wh; dst = Whb; base = blk - 2304; }
    else                 { src = Wo; dst = Wob; base = blk - 2560; }
    size_t i = (size_t)base * 1024 + threadIdx.x * 4;
    float4 f = *(const float4*)(src + i);
    ushort4 o;
    o.x = (unsigned short)f2bf_bits(f.x);
    o.y = (unsigned short)f2bf_bits(f.y);
    o.z = (unsigned short)f2bf_bits(f.z);
    o.w = (unsigned short)f2bf_bits(f.w);
    *(ushort4*)(dst + i) = o;
}

// ---- K1: both staging GEMMs in one launch. grid 2048 ------------------------
__global__ __launch_bounds__(256) void gemm_scale_f32_2(
    const unsigned short* __restrict__ X1, const unsigned short* __restrict__ W1,
    float* __restrict__ C1,
    const unsigned short* __restrict__ X2, const unsigned short* __restrict__ W2,
    float* __restrict__ C2, float scale)
{
    const int K = 512, N = 512;
    int blk = blockIdx.x;
    const unsigned short* X; const unsigned short* W; float* C;
    if (blk < 1024) { X = X1; W = W1; C = C1; }
    else            { X = X2; W = W2; C = C2; blk -= 1024; }
    int tid  = threadIdx.x;
    int lane = tid & 63;
    int gw   = blk * 4 + (tid >> 6);
    int nt   = gw & 31;
    int mt   = gw >> 5;
    int r    = lane & 15;
    int kq   = (lane >> 4) * 8;
    const bf16x8* xp = (const bf16x8*)(X + (size_t)(mt * 16 + r) * K + kq);
    const bf16x8* wp = (const bf16x8*)(W + (size_t)(nt * 16 + r) * K + kq);
    floatx4 acc = {0.f, 0.f, 0.f, 0.f};
#pragma unroll
    for (int k = 0; k < 16; ++k)
        acc = __builtin_amdgcn_mfma_f32_16x16x32_bf16(xp[k * 4], wp[k * 4], acc, 0, 0, 0);
    int row0 = (lane >> 4) * 4;
    float* cp = C + (size_t)(mt * 16 + row0) * N + nt * 16 + r;
#pragma unroll
    for (int i = 0; i < 4; ++i) cp[i * N] = scale * acc[i];
}

// ---- K2: zero E (2 MB). 512 blocks x 256 thr x 1 float4 ---------------------
__global__ __launch_bounds__(256) void zero_E(float* __restrict__ E)
{
    size_t i = ((size_t)blockIdx.x * 256 + threadIdx.x) * 4;
    *(float4*)(E + i) = float4{0.f, 0.f, 0.f, 0.f};
}

// ---- K3: partial energies. 2048 blocks = (ttile<<6)|(sq<<5)|(hq<<3)|b -------
// b in LOW bits: consecutive blocks hit different batches (load balance).
// Wave w owns t-row (ttile*8+w); lane owns s = sq*128 + 64j + lane, j<jmax<=2.
#define HC 32
__global__ __launch_bounds__(512) void energies_partial(
    const float* __restrict__ Aq,          // 2048x512 scaled Ws_q
    const float* __restrict__ Bh,          // 2048x512 scaled Wh_e
    const float* __restrict__ Vv,          // fp32 512
    const int* __restrict__ Len,
    float* __restrict__ E)                 // fp32 2048x256, pre-zeroed
{
    __shared__ float sB[128][HC + 1];
    __shared__ float sA[8][HC];
    __shared__ float sV[128];

    const int H = 512;
    int tid   = threadIdx.x;
    int lane  = tid & 63;
    int w     = tid >> 6;                 // 0..7
    int b     = blockIdx.x & 7;
    int hq    = (blockIdx.x >> 3) & 3;
    int sq    = (blockIdx.x >> 5) & 1;
    int ttile = blockIdx.x >> 6;          // 0..31
    int row0g = b * 256 + ttile * 8;
    int len   = Len[b];
    int sbase = sq * 128;
    if (sbase >= len) return;             // uniform early exit
    int rem   = len - sbase; if (rem > 128) rem = 128;
    int jmax  = (rem + 63) >> 6;          // 1 or 2

    if (tid < 128) sV[tid] = -2.0f * Vv[hq * 128 + tid];

    float acc[2] = {0.f, 0.f};

    for (int hc = 0; hc < 128; hc += HC) {
        __syncthreads();
        {   // stage Wh_e' chunk: 128 rows x HC, 8 floats per thread
            int row = tid >> 2;
            int cb  = (tid & 3) * 8;
            const float* src = Bh + (size_t)(b * 256 + sbase + row) * H + hq * 128 + hc + cb;
            float4 f0 = ((const float4*)src)[0];
            float4 f1 = ((const float4*)src)[1];
            float* dst = &sB[row][cb];
            dst[0]=f0.x; dst[1]=f0.y; dst[2]=f0.z; dst[3]=f0.w;
            dst[4]=f1.x; dst[5]=f1.y; dst[6]=f1.z; dst[7]=f1.w;
        }
        if (tid < 256) {                  // stage Ws_q' chunk: 8 rows x HC
            int row = tid >> 5, col = tid & 31;
            sA[row][col] = Aq[(size_t)(row0g + row) * H + hq * 128 + hc + col];
        }
        __syncthreads();

#pragma unroll
        for (int j = 0; j < 2; ++j) {
            if (j < jmax) {               // uniform per-block branch
                int s = lane + 64 * j;
#pragma unroll
                for (int hh = 0; hh < HC; ++hh) {
                    float e = fexp2(sA[w][hh] + sB[s][hh]);
                    acc[j] += sV[hc + hh] * frcp(1.0f + e);
                }
            }
        }
    }

    float* erow = E + (size_t)(row0g + w) * 256 + sbase;
#pragma unroll
    for (int j = 0; j < 2; ++j)
        if (j < jmax) atomicAdd(erow + 64 * j + lane, acc[j]);
}

// ---- K4a: softmax over E rows -> bf16 weights. 512 blk x 256 thr (4 waves) --
__global__ __launch_bounds__(256) void softmax_w(
    const float* __restrict__ E,           // fp32 2048x256
    const int* __restrict__ Len,
    unsigned short* __restrict__ Wb)       // bf16 2048x256
{
    int tid  = threadIdx.x;
    int lane = tid & 63;
    int r    = blockIdx.x * 4 + (tid >> 6);
    int len  = Len[r >> 8];
    const float* erow = E + (size_t)r * 256;
    float ev[4];
#pragma unroll
    for (int j = 0; j < 4; ++j) {
        int s = lane + 64 * j;
        ev[j] = (s < len) ? erow[s] : NEGBIG;
    }
    float m = fmaxf(fmaxf(ev[0], ev[1]), fmaxf(ev[2], ev[3]));
#pragma unroll
    for (int o = 1; o < 64; o <<= 1) m = fmaxf(m, __shfl_xor(m, o, 64));
    float wv[4];
    float wsum = 0.f;
#pragma unroll
    for (int j = 0; j < 4; ++j) { wv[j] = fexp2((ev[j] - m) * LOG2E); wsum += wv[j]; }
#pragma unroll
    for (int o = 1; o < 64; o <<= 1) wsum += __shfl_xor(wsum, o, 64);
    float inv = frcp(wsum);
    unsigned short* wrow = Wb + (size_t)r * 256;
#pragma unroll
    for (int j = 0; j < 4; ++j)
        wrow[lane + 64 * j] = (unsigned short)f2bf_bits(wv[j] * inv);  // exact 0 beyond len
}

// ---- K4b: ctx = Wb @ enc via MFMA. 256 blocks = (tg<<6)|(hq<<3)|b, 512 thr --
// Per block: b, 64 h (hq), 64 t (tg). EncT tile (64h x 256s) via LDS transpose.
__global__ __launch_bounds__(512) void ctx_gemm(
    const unsigned short* __restrict__ Wb,   // bf16 2048x256 (rows t, cols s)
    const unsigned short* __restrict__ Eb,   // bf16 8x256x512
    unsigned short* __restrict__ Ctx)        // bf16 2048x512
{
    __shared__ unsigned short EncT[64][264];  // 264 u16 stride: 16B-aligned rows, 2-way banks
    int tid = threadIdx.x, lane = tid & 63, w = tid >> 6;
    int blk = blockIdx.x;
    int b = blk & 7, hq = (blk >> 3) & 7, tg = blk >> 6;
    {   // stage + transpose: thread (s, 32-h half)
        int s = tid >> 1, hg = (tid & 1) * 32;
        const ushort4* src = (const ushort4*)(Eb + (size_t)(b * 256 + s) * 512 + hq * 64 + hg);
#pragma unroll
        for (int k = 0; k < 8; ++k) {
            ushort4 u = src[k];
            EncT[hg + k * 4 + 0][s] = u.x;
            EncT[hg + k * 4 + 1][s] = u.y;
            EncT[hg + k * 4 + 2][s] = u.z;
            EncT[hg + k * 4 + 3][s] = u.w;
        }
    }
    __syncthreads();
    int mt = w & 3, npair = w >> 2;          // wave: 16 t x 32 h (2 n-tiles)
    int t0 = tg * 64 + mt * 16;
    int r  = lane & 15, kq = (lane >> 4) * 8;
    const unsigned short* ap = Wb + (size_t)(b * 256 + t0 + r) * 256 + kq;
    int n0 = npair * 32 + r;
    floatx4 acc0 = {0.f,0.f,0.f,0.f}, acc1 = {0.f,0.f,0.f,0.f};
#pragma unroll
    for (int k = 0; k < 8; ++k) {
        bf16x8 a  = *(const bf16x8*)(ap + 32 * k);
        bf16x8 b0 = *(const bf16x8*)(&EncT[n0][kq + 32 * k]);
        bf16x8 b1 = *(const bf16x8*)(&EncT[n0 + 16][kq + 32 * k]);
        acc0 = __builtin_amdgcn_mfma_f32_16x16x32_bf16(a, b0, acc0, 0, 0, 0);
        acc1 = __builtin_amdgcn_mfma_f32_16x16x32_bf16(a, b1, acc1, 0, 0, 0);
    }
    int row0 = (lane >> 4) * 4;
    unsigned short* op = Ctx + (size_t)(b * 256 + t0 + row0) * 512 + hq * 64 + npair * 32 + r;
#pragma unroll
    for (int i = 0; i < 4; ++i) {
        op[i * 512]      = (unsigned short)f2bf_bits(acc0[i]);
        op[i * 512 + 16] = (unsigned short)f2bf_bits(acc1[i]);
    }
}

// ---- K5: out = tanh([ctx|q] @ Wout^T) ---------------------------------------
__global__ __launch_bounds__(256) void out_gemm_tanh(
    const unsigned short* __restrict__ Ctx, const unsigned short* __restrict__ Q,
    const unsigned short* __restrict__ Wout, float* __restrict__ Out)
{
    const int K = 512, N = 512, KW = 1024;
    int tid  = threadIdx.x;
    int lane = tid & 63;
    int gw   = blockIdx.x * 4 + (tid >> 6);
    int nt   = gw & 31;
    int mt   = gw >> 5;
    int r    = lane & 15;
    int kq   = (lane >> 4) * 8;
    const bf16x8* cp  = (const bf16x8*)(Ctx  + (size_t)(mt * 16 + r) * K + kq);
    const bf16x8* qp  = (const bf16x8*)(Q    + (size_t)(mt * 16 + r) * K + kq);
    const bf16x8* wp  = (const bf16x8*)(Wout + (size_t)(nt * 16 + r) * KW + kq);
    const bf16x8* wp2 = (const bf16x8*)(Wout + (size_t)(nt * 16 + r) * KW + 512 + kq);
    floatx4 acc = {0.f, 0.f, 0.f, 0.f};
#pragma unroll
    for (int k = 0; k < 16; ++k)
        acc = __builtin_amdgcn_mfma_f32_16x16x32_bf16(cp[k * 4], wp[k * 4], acc, 0, 0, 0);
#pragma unroll
    for (int k = 0; k < 16; ++k)
        acc = __builtin_amdgcn_mfma_f32_16x16x32_bf16(qp[k * 4], wp2[k * 4], acc, 0, 0, 0);
    int row0 = (lane >> 4) * 4;
    float* op = Out + (size_t)(mt * 16 + row0) * N + nt * 16 + r;
#pragma unroll
    for (int i = 0; i < 4; ++i) {
        float t = 1.0f - 2.0f * frcp(1.0f + fexp2(C2LOG2E * acc[i]));
        op[i * N] = t;
    }
}

extern "C" void kernel_launch(void* const* d_in, const int* in_sizes, int n_in,
                              void* d_out, int out_size, void* d_ws, size_t ws_size,
                              hipStream_t stream)
{
    const float* query = (const float*)d_in[0]; // fp32 8x256x512
    const float* enc   = (const float*)d_in[1]; // fp32 8x256x512
    const int*   len   = (const int*)d_in[2];   // int32 8
    const float* Ws    = (const float*)d_in[3]; // fp32 512x512
    const float* Wh    = (const float*)d_in[4]; // fp32 512x512
    const float* v     = (const float*)d_in[5]; // fp32 512
    const float* Wout  = (const float*)d_in[6]; // fp32 512x1024
    float* out = (float*)d_out;                 // fp32 8x256x512

    float* wsq = (float*)d_ws;                                  // [0,4) MB
    float* whe = wsq + 2048 * 512;                              // [4,8) MB
    float* E   = whe + 2048 * 512;                              // [8,10) MB fp32 2048x256
    unsigned short* ctx = (unsigned short*)E;                   // aliases E (E dead first)
    unsigned short* qb  = (unsigned short*)(E + 2048 * 256);    // [10,12) MB
    unsigned short* eb  = qb + 2048 * 512;                      // [12,14) MB
    unsigned short* Wsb = eb + 2048 * 512;                      // [14,14.5) MB
    unsigned short* Whb = Wsb + 512 * 512;                      // [14.5,15) MB
    unsigned short* Wb  = Wsb;                                  // aliases Wsb+Whb (dead after K1)
    unsigned short* Wob = Whb + 512 * 512;                      // [15,16) MB

    cast_all_bf16<<<3072, 256, 0, stream>>>(query, enc, Ws, Wh, Wout,
                                            qb, eb, Wsb, Whb, Wob);
    gemm_scale_f32_2<<<2048, 256, 0, stream>>>(qb, Wsb, wsq, eb, Whb, whe, C2LOG2E);
    zero_E<<<512, 256, 0, stream>>>(E);
    energies_partial<<<2048, 512, 0, stream>>>(wsq, whe, v, len, E);
    softmax_w<<<512, 256, 0, stream>>>(E, len, Wb);
    ctx_gemm<<<256, 512, 0, stream>>>(Wb, eb, ctx);
    out_gemm_tanh<<<1024, 256, 0, stream>>>(ctx, qb, Wob, out);
}

// Round 5
// 189.912 us; speedup vs baseline: 1.2577x; 1.0402x over previous
//
#include <hip/hip_runtime.h>
#include <hip/hip_bf16.h>

// BahdanauAttention on MI355X (gfx950). ALL float I/O is fp32.
// Internal compute uses bf16 MFMA (no fp32 MFMA on CDNA4).
// Pipeline (5 launches):
//  K0: cast fp32->bf16 for query/enc/W_s/W_h/W_out into ws; zero E
//  K1: A = tanh(query @ W_s^T), B = tanh(enc @ W_h^T)  fp32 [MFMA bf16]
//  K2: energies[t][s] += sum_h v_h*(A+B)/(1+A*B)  (tanh addition formula,
//      no exp2 in the 168M-element loop) -> atomicAdd fp32 E[2048][256]
//  K3: softmax(E, len) -> LDS bf16 weights; ctx tile = W @ enc [MFMA, fused]
//  K4: out = tanh([ctx|query] @ W_out^T) -> fp32 d_out [MFMA bf16]
// ws aliases: ctx over wsq/A (A dead after K2). 16 MB total.

typedef __attribute__((ext_vector_type(8))) short bf16x8;
typedef __attribute__((ext_vector_type(4))) float floatx4;

#define C2LOG2E 2.8853900817779268f   // 2*log2(e)
#define LOG2E   1.4426950408889634f
#define NEGBIG  -1e30f

__device__ __forceinline__ float fexp2(float x) { return __builtin_amdgcn_exp2f(x); }
__device__ __forceinline__ float frcp(float x)  { return __builtin_amdgcn_rcpf(x); }
__device__ __forceinline__ float ftanh(float x) {            // exact enough; used on small arrays only
    return 1.0f - 2.0f * frcp(1.0f + fexp2(C2LOG2E * x));
}

__device__ __forceinline__ unsigned int f2bf_bits(float f) {
    unsigned int u = __float_as_uint(f);
    return (u + 0x7fffu + ((u >> 16) & 1u)) >> 16;   // RNE (inputs finite)
}

// ---- K0: cast fp32 -> bf16 (+ zero E). 3584 blocks x 256 thr ----------------
__global__ __launch_bounds__(256) void cast_all_bf16(
    const float* __restrict__ q,  const float* __restrict__ e,
    const float* __restrict__ Ws, const float* __restrict__ Wh,
    const float* __restrict__ Wo,
    unsigned short* __restrict__ qb,  unsigned short* __restrict__ eb,
    unsigned short* __restrict__ Wsb, unsigned short* __restrict__ Whb,
    unsigned short* __restrict__ Wob, float* __restrict__ E)
{
    int blk = blockIdx.x;
    if (blk >= 3072) {  // zero E: 512 blocks x 1024 floats
        size_t i = ((size_t)(blk - 3072) * 256 + threadIdx.x) * 4;
        *(float4*)(E + i) = float4{0.f, 0.f, 0.f, 0.f};
        return;
    }
    const float* src; unsigned short* dst; int base;
    if      (blk < 1024) { src = q;  dst = qb;  base = blk; }
    else if (blk < 2048) { src = e;  dst = eb;  base = blk - 1024; }
    else if (blk < 2304) { src = Ws; dst = Wsb; base = blk - 2048; }
    else if (blk < 2560) { src = Wh; dst = Whb; base = blk - 2304; }
    else                 { src = Wo; dst = Wob; base = blk - 2560; }
    size_t i = (size_t)base * 1024 + threadIdx.x * 4;
    float4 f = *(const float4*)(src + i);
    ushort4 o;
    o.x = (unsigned short)f2bf_bits(f.x);
    o.y = (unsigned short)f2bf_bits(f.y);
    o.z = (unsigned short)f2bf_bits(f.z);
    o.w = (unsigned short)f2bf_bits(f.w);
    *(ushort4*)(dst + i) = o;
}

// ---- K1: A=tanh(q@Ws^T), B=tanh(e@Wh^T), one launch, grid 2048 --------------
__global__ __launch_bounds__(256) void gemm_tanh_2(
    const unsigned short* __restrict__ X1, const unsigned short* __restrict__ W1,
    float* __restrict__ C1,
    const unsigned short* __restrict__ X2, const unsigned short* __restrict__ W2,
    float* __restrict__ C2)
{
    const int K = 512, N = 512;
    int blk = blockIdx.x;
    const unsigned short* X; const unsigned short* W; float* C;
    if (blk < 1024) { X = X1; W = W1; C = C1; }
    else            { X = X2; W = W2; C = C2; blk -= 1024; }
    int tid  = threadIdx.x;
    int lane = tid & 63;
    int gw   = blk * 4 + (tid >> 6);
    int nt   = gw & 31;
    int mt   = gw >> 5;
    int r    = lane & 15;
    int kq   = (lane >> 4) * 8;
    const bf16x8* xp = (const bf16x8*)(X + (size_t)(mt * 16 + r) * K + kq);
    const bf16x8* wp = (const bf16x8*)(W + (size_t)(nt * 16 + r) * K + kq);
    floatx4 acc = {0.f, 0.f, 0.f, 0.f};
#pragma unroll
    for (int k = 0; k < 16; ++k)
        acc = __builtin_amdgcn_mfma_f32_16x16x32_bf16(xp[k * 4], wp[k * 4], acc, 0, 0, 0);
    int row0 = (lane >> 4) * 4;
    float* cp = C + (size_t)(mt * 16 + row0) * N + nt * 16 + r;
#pragma unroll
    for (int i = 0; i < 4; ++i) cp[i * N] = ftanh(acc[i]);
}

// ---- K2: energies. 1024 blocks = (ttile<<5)|(hq<<3)|b, 512 thr --------------
// Wave w owns t-row (ttile*8+w); lane owns s = 64j+lane, j<jmax; h slice hq*128.
// Inner: acc_j += v_h * (A+B)/(1+A*B).  A uniform per (w,h); B via b128 LDS.
#define HC 32
__global__ __launch_bounds__(512) void energies_partial(
    const float* __restrict__ Aq,          // 2048x512 tanh(Ws_q)
    const float* __restrict__ Bh,          // 2048x512 tanh(Wh_e)
    const float* __restrict__ Vv,          // fp32 512
    const int* __restrict__ Len,
    float* __restrict__ E)                 // fp32 2048x256, pre-zeroed
{
    __shared__ float sB[256][36];          // stride 36: b128-aligned hh-quads
    __shared__ float sA[8][36];
    __shared__ float sV[128];

    const int H = 512;
    int tid   = threadIdx.x;
    int lane  = tid & 63;
    int w     = tid >> 6;
    int b     = blockIdx.x & 7;            // b in LOW bits: load balance
    int hq    = (blockIdx.x >> 3) & 3;
    int ttile = blockIdx.x >> 5;
    int row0g = b * 256 + ttile * 8;
    int len   = Len[b];
    int jmax  = (len + 63) >> 6;           // 1..4

    if (tid < 128) sV[tid] = Vv[hq * 128 + tid];

    float acc[4] = {0.f, 0.f, 0.f, 0.f};

    for (int hc = 0; hc < 128; hc += HC) {
        __syncthreads();
        {   // stage B chunk: 256 rows x HC, 16 floats per thread
            int row = tid >> 1;
            int cb  = (tid & 1) * 16;
            const float* src = Bh + (size_t)(b * 256 + row) * H + hq * 128 + hc + cb;
            float4 f0 = ((const float4*)src)[0];
            float4 f1 = ((const float4*)src)[1];
            float4 f2 = ((const float4*)src)[2];
            float4 f3 = ((const float4*)src)[3];
            float* dst = &sB[row][cb];
            *(float4*)(dst + 0)  = f0;
            *(float4*)(dst + 4)  = f1;
            *(float4*)(dst + 8)  = f2;
            *(float4*)(dst + 12) = f3;
        }
        if (tid < 256) {                   // stage A chunk: 8 rows x HC
            int row = tid >> 5, col = tid & 31;
            sA[row][col] = Aq[(size_t)(row0g + row) * H + hq * 128 + hc + col];
        }
        __syncthreads();

#pragma unroll
        for (int hh = 0; hh < HC; hh += 4) {
            float4 a4 = *(const float4*)&sA[w][hh];       // uniform b128
            float4 v4 = *(const float4*)&sV[hc + hh];     // uniform b128
#pragma unroll
            for (int j = 0; j < 4; ++j) {
                if (j < jmax) {            // uniform per-block branch
                    int s = lane + 64 * j;
                    float4 b4 = *(const float4*)&sB[s][hh];
                    acc[j] = fmaf(v4.x, (a4.x + b4.x) * frcp(fmaf(a4.x, b4.x, 1.0f)), acc[j]);
                    acc[j] = fmaf(v4.y, (a4.y + b4.y) * frcp(fmaf(a4.y, b4.y, 1.0f)), acc[j]);
                    acc[j] = fmaf(v4.z, (a4.z + b4.z) * frcp(fmaf(a4.z, b4.z, 1.0f)), acc[j]);
                    acc[j] = fmaf(v4.w, (a4.w + b4.w) * frcp(fmaf(a4.w, b4.w, 1.0f)), acc[j]);
                }
            }
        }
    }

    float* erow = E + (size_t)(row0g + w) * 256;
#pragma unroll
    for (int j = 0; j < 4; ++j)
        if (j < jmax) atomicAdd(erow + 64 * j + lane, acc[j]);
}

// ---- K3: fused softmax + ctx GEMM. 256 blocks = (tg<<6)|(hq<<3)|b, 512 thr --
// Softmax of 64 t-rows (redundant per hq, cheap) -> bf16 weights in LDS;
// EncT (64h x 256s) via LDS transpose; MFMA 16x16x32.
__global__ __launch_bounds__(512) void softmax_ctx_fused(
    const float* __restrict__ E,             // fp32 2048x256
    const unsigned short* __restrict__ Eb,   // bf16 8x256x512
    const int* __restrict__ Len,
    unsigned short* __restrict__ Ctx)        // bf16 2048x512
{
    __shared__ unsigned short EncT[64][264];
    __shared__ unsigned short sWb[64][264];
    int tid = threadIdx.x, lane = tid & 63, w = tid >> 6;
    int blk = blockIdx.x;
    int b = blk & 7, hq = (blk >> 3) & 7, tg = blk >> 6;
    int len = Len[b];

    {   // stage + transpose enc tile: thread (s, 32-h half)
        int s = tid >> 1, hg = (tid & 1) * 32;
        const ushort4* src = (const ushort4*)(Eb + (size_t)(b * 256 + s) * 512 + hq * 64 + hg);
#pragma unroll
        for (int k = 0; k < 8; ++k) {
            ushort4 u = src[k];
            EncT[hg + k * 4 + 0][s] = u.x;
            EncT[hg + k * 4 + 1][s] = u.y;
            EncT[hg + k * 4 + 2][s] = u.z;
            EncT[hg + k * 4 + 3][s] = u.w;
        }
    }
    // softmax: wave w owns rows w*8 .. w*8+7 of the 64-row tile
    for (int i = 0; i < 8; ++i) {
        int row = w * 8 + i;
        const float* erow = E + (size_t)(b * 256 + tg * 64 + row) * 256;
        float ev[4];
#pragma unroll
        for (int j = 0; j < 4; ++j) {
            int s = lane + 64 * j;
            ev[j] = (s < len) ? erow[s] : NEGBIG;
        }
        float m = fmaxf(fmaxf(ev[0], ev[1]), fmaxf(ev[2], ev[3]));
#pragma unroll
        for (int o = 1; o < 64; o <<= 1) m = fmaxf(m, __shfl_xor(m, o, 64));
        float wv[4], wsum = 0.f;
#pragma unroll
        for (int j = 0; j < 4; ++j) { wv[j] = fexp2((ev[j] - m) * LOG2E); wsum += wv[j]; }
#pragma unroll
        for (int o = 1; o < 64; o <<= 1) wsum += __shfl_xor(wsum, o, 64);
        float inv = frcp(wsum);
#pragma unroll
        for (int j = 0; j < 4; ++j)
            sWb[row][lane + 64 * j] = (unsigned short)f2bf_bits(wv[j] * inv);  // exact 0 beyond len
    }
    __syncthreads();

    int mt = w & 3, npair = w >> 2;          // wave: 16 t x 32 h (2 n-tiles)
    int t0 = mt * 16;
    int r  = lane & 15, kq = (lane >> 4) * 8;
    int n0 = npair * 32 + r;
    floatx4 acc0 = {0.f,0.f,0.f,0.f}, acc1 = {0.f,0.f,0.f,0.f};
#pragma unroll
    for (int k = 0; k < 8; ++k) {
        bf16x8 a  = *(const bf16x8*)(&sWb[t0 + r][kq + 32 * k]);
        bf16x8 b0 = *(const bf16x8*)(&EncT[n0][kq + 32 * k]);
        bf16x8 b1 = *(const bf16x8*)(&EncT[n0 + 16][kq + 32 * k]);
        acc0 = __builtin_amdgcn_mfma_f32_16x16x32_bf16(a, b0, acc0, 0, 0, 0);
        acc1 = __builtin_amdgcn_mfma_f32_16x16x32_bf16(a, b1, acc1, 0, 0, 0);
    }
    int row0 = (lane >> 4) * 4;
    unsigned short* op = Ctx + (size_t)(b * 256 + tg * 64 + t0 + row0) * 512 + hq * 64 + npair * 32 + r;
#pragma unroll
    for (int i = 0; i < 4; ++i) {
        op[i * 512]      = (unsigned short)f2bf_bits(acc0[i]);
        op[i * 512 + 16] = (unsigned short)f2bf_bits(acc1[i]);
    }
}

// ---- K4: out = tanh([ctx|q] @ Wout^T) ---------------------------------------
__global__ __launch_bounds__(256) void out_gemm_tanh(
    const unsigned short* __restrict__ Ctx, const unsigned short* __restrict__ Q,
    const unsigned short* __restrict__ Wout, float* __restrict__ Out)
{
    const int K = 512, N = 512, KW = 1024;
    int tid  = threadIdx.x;
    int lane = tid & 63;
    int gw   = blockIdx.x * 4 + (tid >> 6);
    int nt   = gw & 31;
    int mt   = gw >> 5;
    int r    = lane & 15;
    int kq   = (lane >> 4) * 8;
    const bf16x8* cp  = (const bf16x8*)(Ctx  + (size_t)(mt * 16 + r) * K + kq);
    const bf16x8* qp  = (const bf16x8*)(Q    + (size_t)(mt * 16 + r) * K + kq);
    const bf16x8* wp  = (const bf16x8*)(Wout + (size_t)(nt * 16 + r) * KW + kq);
    const bf16x8* wp2 = (const bf16x8*)(Wout + (size_t)(nt * 16 + r) * KW + 512 + kq);
    floatx4 acc = {0.f, 0.f, 0.f, 0.f};
#pragma unroll
    for (int k = 0; k < 16; ++k)
        acc = __builtin_amdgcn_mfma_f32_16x16x32_bf16(cp[k * 4], wp[k * 4], acc, 0, 0, 0);
#pragma unroll
    for (int k = 0; k < 16; ++k)
        acc = __builtin_amdgcn_mfma_f32_16x16x32_bf16(qp[k * 4], wp2[k * 4], acc, 0, 0, 0);
    int row0 = (lane >> 4) * 4;
    float* op = Out + (size_t)(mt * 16 + row0) * N + nt * 16 + r;
#pragma unroll
    for (int i = 0; i < 4; ++i) op[i * N] = ftanh(acc[i]);
}

extern "C" void kernel_launch(void* const* d_in, const int* in_sizes, int n_in,
                              void* d_out, int out_size, void* d_ws, size_t ws_size,
                              hipStream_t stream)
{
    const float* query = (const float*)d_in[0]; // fp32 8x256x512
    const float* enc   = (const float*)d_in[1]; // fp32 8x256x512
    const int*   len   = (const int*)d_in[2];   // int32 8
    const float* Ws    = (const float*)d_in[3]; // fp32 512x512
    const float* Wh    = (const float*)d_in[4]; // fp32 512x512
    const float* v     = (const float*)d_in[5]; // fp32 512
    const float* Wout  = (const float*)d_in[6]; // fp32 512x1024
    float* out = (float*)d_out;                 // fp32 8x256x512

    float* wsq = (float*)d_ws;                                  // [0,4) MB  A
    float* whe = wsq + 2048 * 512;                              // [4,8) MB  B
    float* E   = whe + 2048 * 512;                              // [8,10) MB fp32 2048x256
    unsigned short* ctx = (unsigned short*)wsq;                 // aliases A (dead after K2)
    unsigned short* qb  = (unsigned short*)(E + 2048 * 256);    // [10,12) MB
    unsigned short* eb  = qb + 2048 * 512;                      // [12,14) MB
    unsigned short* Wsb = eb + 2048 * 512;                      // [14,14.5) MB
    unsigned short* Whb = Wsb + 512 * 512;                      // [14.5,15) MB
    unsigned short* Wob = Whb + 512 * 512;                      // [15,16) MB

    cast_all_bf16<<<3584, 256, 0, stream>>>(query, enc, Ws, Wh, Wout,
                                            qb, eb, Wsb, Whb, Wob, E);
    gemm_tanh_2<<<2048, 256, 0, stream>>>(qb, Wsb, wsq, eb, Whb, whe);
    energies_partial<<<1024, 512, 0, stream>>>(wsq, whe, v, len, E);
    softmax_ctx_fused<<<256, 512, 0, stream>>>(E, eb, len, ctx);
    out_gemm_tanh<<<1024, 256, 0, stream>>>(ctx, qb, Wob, out);
}

// Round 6
// 138.836 us; speedup vs baseline: 1.7204x; 1.3679x over previous
//
#include <hip/hip_runtime.h>
#include <hip/hip_bf16.h>

// BahdanauAttention on MI355X (gfx950). ALL float I/O is fp32.
// Internal compute uses bf16 MFMA (no fp32 MFMA on CDNA4).
// Pipeline (5 launches):
//  K0: cast fp32->bf16 for query/enc/W_s/W_h/W_out into ws; zero E
//  K1: A = tanh(query @ W_s^T), B = tanh(enc @ W_h^T)  [64x64 LDS-tiled MFMA]
//  K2: energies[t][s] += sum_h v_h*(A+B)/(1+A*B) -> atomicAdd fp32 E[2048][256]
//      (tanh addition formula; XCD-balanced grid: ttile in LOW bits)
//  K3: softmax(E, len) -> LDS bf16 weights; ctx tile = W @ enc [MFMA, fused]
//  K4: out = tanh([ctx|query] @ W_out^T)  [64x64 LDS-tiled MFMA, concat-K]
// ws aliases: ctx over wsq/A (A dead after K2). 16 MB total.

typedef __attribute__((ext_vector_type(8))) short bf16x8;
typedef __attribute__((ext_vector_type(4))) float floatx4;

#define C2LOG2E 2.8853900817779268f   // 2*log2(e)
#define LOG2E   1.4426950408889634f
#define NEGBIG  -1e30f

__device__ __forceinline__ float fexp2(float x) { return __builtin_amdgcn_exp2f(x); }
__device__ __forceinline__ float frcp(float x)  { return __builtin_amdgcn_rcpf(x); }
__device__ __forceinline__ float ftanh(float x) {
    return 1.0f - 2.0f * frcp(1.0f + fexp2(C2LOG2E * x));
}

__device__ __forceinline__ unsigned int f2bf_bits(float f) {
    unsigned int u = __float_as_uint(f);
    return (u + 0x7fffu + ((u >> 16) & 1u)) >> 16;   // RNE (inputs finite)
}

// ---- K0: cast fp32 -> bf16 (+ zero E). 3584 blocks x 256 thr ----------------
__global__ __launch_bounds__(256) void cast_all_bf16(
    const float* __restrict__ q,  const float* __restrict__ e,
    const float* __restrict__ Ws, const float* __restrict__ Wh,
    const float* __restrict__ Wo,
    unsigned short* __restrict__ qb,  unsigned short* __restrict__ eb,
    unsigned short* __restrict__ Wsb, unsigned short* __restrict__ Whb,
    unsigned short* __restrict__ Wob, float* __restrict__ E)
{
    int blk = blockIdx.x;
    if (blk >= 3072) {  // zero E: 512 blocks x 1024 floats
        size_t i = ((size_t)(blk - 3072) * 256 + threadIdx.x) * 4;
        *(float4*)(E + i) = float4{0.f, 0.f, 0.f, 0.f};
        return;
    }
    const float* src; unsigned short* dst; int base;
    if      (blk < 1024) { src = q;  dst = qb;  base = blk; }
    else if (blk < 2048) { src = e;  dst = eb;  base = blk - 1024; }
    else if (blk < 2304) { src = Ws; dst = Wsb; base = blk - 2048; }
    else if (blk < 2560) { src = Wh; dst = Whb; base = blk - 2304; }
    else                 { src = Wo; dst = Wob; base = blk - 2560; }
    size_t i = (size_t)base * 1024 + threadIdx.x * 4;
    float4 f = *(const float4*)(src + i);
    ushort4 o;
    o.x = (unsigned short)f2bf_bits(f.x);
    o.y = (unsigned short)f2bf_bits(f.y);
    o.z = (unsigned short)f2bf_bits(f.z);
    o.w = (unsigned short)f2bf_bits(f.w);
    *(ushort4*)(dst + i) = o;
}

// ---- K1: 64x64-tile LDS GEMM, dual: C = tanh(X @ W^T), two pairs ------------
// X: 2048x512 bf16, W: 512x512 bf16, C: fp32. 512 blocks = pair*256 + mt6*8 + nt6.
__global__ __launch_bounds__(256) void gemm64_tanh_dual(
    const unsigned short* __restrict__ X1, const unsigned short* __restrict__ W1,
    float* __restrict__ C1,
    const unsigned short* __restrict__ X2, const unsigned short* __restrict__ W2,
    float* __restrict__ C2)
{
    __shared__ unsigned short sA[64 * 72];
    __shared__ unsigned short sB[64 * 72];
    const int K = 512, N = 512;
    int blk = blockIdx.x;
    const unsigned short* X; const unsigned short* W; float* C;
    if (blk < 256) { X = X1; W = W1; C = C1; }
    else           { X = X2; W = W2; C = C2; blk -= 256; }
    int mt6 = blk >> 3, nt6 = blk & 7;
    int row0 = mt6 * 64, col0 = nt6 * 64;
    int tid = threadIdx.x, lane = tid & 63, w = tid >> 6;
    int srow = tid >> 2, sseg = (tid & 3) * 16;
    int mw = (w & 1) * 32, nw = (w >> 1) * 32;
    int r = lane & 15, kq = (lane >> 4) * 8;

    floatx4 acc00 = {0,0,0,0}, acc01 = {0,0,0,0}, acc10 = {0,0,0,0}, acc11 = {0,0,0,0};
    const unsigned short* ga = X + (size_t)(row0 + srow) * K + sseg;
    const unsigned short* gb = W + (size_t)(col0 + srow) * K + sseg;

    for (int kb = 0; kb < 8; ++kb) {
        uint4 a0 = *(const uint4*)(ga);
        uint4 a1 = *(const uint4*)(ga + 8);
        uint4 b0 = *(const uint4*)(gb);
        uint4 b1 = *(const uint4*)(gb + 8);
        ga += 64; gb += 64;
        __syncthreads();
        *(uint4*)&sA[srow * 72 + sseg]     = a0;
        *(uint4*)&sA[srow * 72 + sseg + 8] = a1;
        *(uint4*)&sB[srow * 72 + sseg]     = b0;
        *(uint4*)&sB[srow * 72 + sseg + 8] = b1;
        __syncthreads();
#pragma unroll
        for (int ks = 0; ks < 64; ks += 32) {
            bf16x8 af0 = *(const bf16x8*)&sA[(mw + r) * 72 + ks + kq];
            bf16x8 af1 = *(const bf16x8*)&sA[(mw + 16 + r) * 72 + ks + kq];
            bf16x8 bf0 = *(const bf16x8*)&sB[(nw + r) * 72 + ks + kq];
            bf16x8 bf1 = *(const bf16x8*)&sB[(nw + 16 + r) * 72 + ks + kq];
            acc00 = __builtin_amdgcn_mfma_f32_16x16x32_bf16(af0, bf0, acc00, 0, 0, 0);
            acc01 = __builtin_amdgcn_mfma_f32_16x16x32_bf16(af0, bf1, acc01, 0, 0, 0);
            acc10 = __builtin_amdgcn_mfma_f32_16x16x32_bf16(af1, bf0, acc10, 0, 0, 0);
            acc11 = __builtin_amdgcn_mfma_f32_16x16x32_bf16(af1, bf1, acc11, 0, 0, 0);
        }
    }
    int rq = (lane >> 4) * 4;
    float* cp = C + (size_t)(row0 + mw + rq) * N + col0 + nw + r;
#pragma unroll
    for (int i = 0; i < 4; ++i) {
        cp[(size_t)i * N]            = ftanh(acc00[i]);
        cp[(size_t)i * N + 16]       = ftanh(acc01[i]);
        cp[(size_t)(i + 16) * N]      = ftanh(acc10[i]);
        cp[(size_t)(i + 16) * N + 16] = ftanh(acc11[i]);
    }
}

// ---- K2: energies. 1024 blocks = (b<<7)|(hq<<5)|ttile (ttile LOW: XCD bal) --
// Wave w owns t-row (ttile*8+w); lane owns s = 64j+lane, j<jmax; h slice hq*128.
#define HC 32
__global__ __launch_bounds__(512) void energies_partial(
    const float* __restrict__ Aq,          // 2048x512 tanh(Ws_q)
    const float* __restrict__ Bh,          // 2048x512 tanh(Wh_e)
    const float* __restrict__ Vv,          // fp32 512
    const int* __restrict__ Len,
    float* __restrict__ E)                 // fp32 2048x256, pre-zeroed
{
    __shared__ float sB[256][36];          // stride 36: b128-aligned hh-quads
    __shared__ float sA[8][36];
    __shared__ float sV[128];

    const int H = 512;
    int tid   = threadIdx.x;
    int lane  = tid & 63;
    int w     = tid >> 6;
    int b     = blockIdx.x >> 7;
    int hq    = (blockIdx.x >> 5) & 3;
    int ttile = blockIdx.x & 31;           // LOW bits: uniform over XCDs
    int row0g = b * 256 + ttile * 8;
    int len   = Len[b];
    int jmax  = (len + 63) >> 6;           // 1..4

    if (tid < 128) sV[tid] = Vv[hq * 128 + tid];

    float acc[4] = {0.f, 0.f, 0.f, 0.f};

    for (int hc = 0; hc < 128; hc += HC) {
        __syncthreads();
        {   // stage B chunk: 256 rows x HC, 16 floats per thread
            int row = tid >> 1;
            int cb  = (tid & 1) * 16;
            const float* src = Bh + (size_t)(b * 256 + row) * H + hq * 128 + hc + cb;
            float4 f0 = ((const float4*)src)[0];
            float4 f1 = ((const float4*)src)[1];
            float4 f2 = ((const float4*)src)[2];
            float4 f3 = ((const float4*)src)[3];
            float* dst = &sB[row][cb];
            *(float4*)(dst + 0)  = f0;
            *(float4*)(dst + 4)  = f1;
            *(float4*)(dst + 8)  = f2;
            *(float4*)(dst + 12) = f3;
        }
        if (tid < 256) {                   // stage A chunk: 8 rows x HC
            int row = tid >> 5, col = tid & 31;
            sA[row][col] = Aq[(size_t)(row0g + row) * H + hq * 128 + hc + col];
        }
        __syncthreads();

#pragma unroll
        for (int hh = 0; hh < HC; hh += 4) {
            float4 a4 = *(const float4*)&sA[w][hh];       // uniform b128
            float4 v4 = *(const float4*)&sV[hc + hh];     // uniform b128
#pragma unroll
            for (int j = 0; j < 4; ++j) {
                if (j < jmax) {            // uniform per-block branch
                    int s = lane + 64 * j;
                    float4 b4 = *(const float4*)&sB[s][hh];
                    acc[j] = fmaf(v4.x, (a4.x + b4.x) * frcp(fmaf(a4.x, b4.x, 1.0f)), acc[j]);
                    acc[j] = fmaf(v4.y, (a4.y + b4.y) * frcp(fmaf(a4.y, b4.y, 1.0f)), acc[j]);
                    acc[j] = fmaf(v4.z, (a4.z + b4.z) * frcp(fmaf(a4.z, b4.z, 1.0f)), acc[j]);
                    acc[j] = fmaf(v4.w, (a4.w + b4.w) * frcp(fmaf(a4.w, b4.w, 1.0f)), acc[j]);
                }
            }
        }
    }

    float* erow = E + (size_t)(row0g + w) * 256;
#pragma unroll
    for (int j = 0; j < 4; ++j)
        if (j < jmax) atomicAdd(erow + 64 * j + lane, acc[j]);
}

// ---- K3: fused softmax + ctx GEMM. 256 blocks = (tg<<6)|(hq<<3)|b, 512 thr --
__global__ __launch_bounds__(512) void softmax_ctx_fused(
    const float* __restrict__ E,             // fp32 2048x256
    const unsigned short* __restrict__ Eb,   // bf16 8x256x512
    const int* __restrict__ Len,
    unsigned short* __restrict__ Ctx)        // bf16 2048x512
{
    __shared__ unsigned short EncT[64][264];
    __shared__ unsigned short sWb[64][264];
    int tid = threadIdx.x, lane = tid & 63, w = tid >> 6;
    int blk = blockIdx.x;
    int b = blk & 7, hq = (blk >> 3) & 7, tg = blk >> 6;
    int len = Len[b];

    {   // stage + transpose enc tile: thread (s, 32-h half)
        int s = tid >> 1, hg = (tid & 1) * 32;
        const ushort4* src = (const ushort4*)(Eb + (size_t)(b * 256 + s) * 512 + hq * 64 + hg);
#pragma unroll
        for (int k = 0; k < 8; ++k) {
            ushort4 u = src[k];
            EncT[hg + k * 4 + 0][s] = u.x;
            EncT[hg + k * 4 + 1][s] = u.y;
            EncT[hg + k * 4 + 2][s] = u.z;
            EncT[hg + k * 4 + 3][s] = u.w;
        }
    }
    // softmax: wave w owns rows w*8 .. w*8+7 of the 64-row tile
    for (int i = 0; i < 8; ++i) {
        int row = w * 8 + i;
        const float* erow = E + (size_t)(b * 256 + tg * 64 + row) * 256;
        float ev[4];
#pragma unroll
        for (int j = 0; j < 4; ++j) {
            int s = lane + 64 * j;
            ev[j] = (s < len) ? erow[s] : NEGBIG;
        }
        float m = fmaxf(fmaxf(ev[0], ev[1]), fmaxf(ev[2], ev[3]));
#pragma unroll
        for (int o = 1; o < 64; o <<= 1) m = fmaxf(m, __shfl_xor(m, o, 64));
        float wv[4], wsum = 0.f;
#pragma unroll
        for (int j = 0; j < 4; ++j) { wv[j] = fexp2((ev[j] - m) * LOG2E); wsum += wv[j]; }
#pragma unroll
        for (int o = 1; o < 64; o <<= 1) wsum += __shfl_xor(wsum, o, 64);
        float inv = frcp(wsum);
#pragma unroll
        for (int j = 0; j < 4; ++j)
            sWb[row][lane + 64 * j] = (unsigned short)f2bf_bits(wv[j] * inv);
    }
    __syncthreads();

    int mt = w & 3, npair = w >> 2;          // wave: 16 t x 32 h (2 n-tiles)
    int t0 = mt * 16;
    int r  = lane & 15, kq = (lane >> 4) * 8;
    int n0 = npair * 32 + r;
    floatx4 acc0 = {0.f,0.f,0.f,0.f}, acc1 = {0.f,0.f,0.f,0.f};
#pragma unroll
    for (int k = 0; k < 8; ++k) {
        bf16x8 a  = *(const bf16x8*)(&sWb[t0 + r][kq + 32 * k]);
        bf16x8 b0 = *(const bf16x8*)(&EncT[n0][kq + 32 * k]);
        bf16x8 b1 = *(const bf16x8*)(&EncT[n0 + 16][kq + 32 * k]);
        acc0 = __builtin_amdgcn_mfma_f32_16x16x32_bf16(a, b0, acc0, 0, 0, 0);
        acc1 = __builtin_amdgcn_mfma_f32_16x16x32_bf16(a, b1, acc1, 0, 0, 0);
    }
    int row0 = (lane >> 4) * 4;
    unsigned short* op = Ctx + (size_t)(b * 256 + tg * 64 + t0 + row0) * 512 + hq * 64 + npair * 32 + r;
#pragma unroll
    for (int i = 0; i < 4; ++i) {
        op[i * 512]      = (unsigned short)f2bf_bits(acc0[i]);
        op[i * 512 + 16] = (unsigned short)f2bf_bits(acc1[i]);
    }
}

// ---- K4: 64x64-tile LDS GEMM, concat-K: out = tanh([ctx|q] @ Wout^T) --------
// A = ctx (k<512) then qb (k>=512), both 2048x512 bf16; Wout 512x1024 bf16.
__global__ __launch_bounds__(256) void out_gemm64_tanh(
    const unsigned short* __restrict__ Ctx, const unsigned short* __restrict__ Q,
    const unsigned short* __restrict__ Wout, float* __restrict__ Out)
{
    __shared__ unsigned short sA[64 * 72];
    __shared__ unsigned short sB[64 * 72];
    const int N = 512, KW = 1024;
    int blk = blockIdx.x;
    int mt6 = blk >> 3, nt6 = blk & 7;
    int row0 = mt6 * 64, col0 = nt6 * 64;
    int tid = threadIdx.x, lane = tid & 63, w = tid >> 6;
    int srow = tid >> 2, sseg = (tid & 3) * 16;
    int mw = (w & 1) * 32, nw = (w >> 1) * 32;
    int r = lane & 15, kq = (lane >> 4) * 8;

    floatx4 acc00 = {0,0,0,0}, acc01 = {0,0,0,0}, acc10 = {0,0,0,0}, acc11 = {0,0,0,0};
    const unsigned short* gb = Wout + (size_t)(col0 + srow) * KW + sseg;

    for (int kb = 0; kb < 16; ++kb) {
        const unsigned short* asrc = (kb < 8 ? Ctx : Q);
        const unsigned short* ga = asrc + (size_t)(row0 + srow) * 512 + (kb & 7) * 64 + sseg;
        uint4 a0 = *(const uint4*)(ga);
        uint4 a1 = *(const uint4*)(ga + 8);
        uint4 b0 = *(const uint4*)(gb);
        uint4 b1 = *(const uint4*)(gb + 8);
        gb += 64;
        __syncthreads();
        *(uint4*)&sA[srow * 72 + sseg]     = a0;
        *(uint4*)&sA[srow * 72 + sseg + 8] = a1;
        *(uint4*)&sB[srow * 72 + sseg]     = b0;
        *(uint4*)&sB[srow * 72 + sseg + 8] = b1;
        __syncthreads();
#pragma unroll
        for (int ks = 0; ks < 64; ks += 32) {
            bf16x8 af0 = *(const bf16x8*)&sA[(mw + r) * 72 + ks + kq];
            bf16x8 af1 = *(const bf16x8*)&sA[(mw + 16 + r) * 72 + ks + kq];
            bf16x8 bf0 = *(const bf16x8*)&sB[(nw + r) * 72 + ks + kq];
            bf16x8 bf1 = *(const bf16x8*)&sB[(nw + 16 + r) * 72 + ks + kq];
            acc00 = __builtin_amdgcn_mfma_f32_16x16x32_bf16(af0, bf0, acc00, 0, 0, 0);
            acc01 = __builtin_amdgcn_mfma_f32_16x16x32_bf16(af0, bf1, acc01, 0, 0, 0);
            acc10 = __builtin_amdgcn_mfma_f32_16x16x32_bf16(af1, bf0, acc10, 0, 0, 0);
            acc11 = __builtin_amdgcn_mfma_f32_16x16x32_bf16(af1, bf1, acc11, 0, 0, 0);
        }
    }
    int rq = (lane >> 4) * 4;
    float* op = Out + (size_t)(row0 + mw + rq) * N + col0 + nw + r;
#pragma unroll
    for (int i = 0; i < 4; ++i) {
        op[(size_t)i * N]             = ftanh(acc00[i]);
        op[(size_t)i * N + 16]        = ftanh(acc01[i]);
        op[(size_t)(i + 16) * N]      = ftanh(acc10[i]);
        op[(size_t)(i + 16) * N + 16] = ftanh(acc11[i]);
    }
}

extern "C" void kernel_launch(void* const* d_in, const int* in_sizes, int n_in,
                              void* d_out, int out_size, void* d_ws, size_t ws_size,
                              hipStream_t stream)
{
    const float* query = (const float*)d_in[0]; // fp32 8x256x512
    const float* enc   = (const float*)d_in[1]; // fp32 8x256x512
    const int*   len   = (const int*)d_in[2];   // int32 8
    const float* Ws    = (const float*)d_in[3]; // fp32 512x512
    const float* Wh    = (const float*)d_in[4]; // fp32 512x512
    const float* v     = (const float*)d_in[5]; // fp32 512
    const float* Wout  = (const float*)d_in[6]; // fp32 512x1024
    float* out = (float*)d_out;                 // fp32 8x256x512

    float* wsq = (float*)d_ws;                                  // [0,4) MB  A
    float* whe = wsq + 2048 * 512;                              // [4,8) MB  B
    float* E   = whe + 2048 * 512;                              // [8,10) MB fp32 2048x256
    unsigned short* ctx = (unsigned short*)wsq;                 // aliases A (dead after K2)
    unsigned short* qb  = (unsigned short*)(E + 2048 * 256);    // [10,12) MB
    unsigned short* eb  = qb + 2048 * 512;                      // [12,14) MB
    unsigned short* Wsb = eb + 2048 * 512;                      // [14,14.5) MB
    unsigned short* Whb = Wsb + 512 * 512;                      // [14.5,15) MB
    unsigned short* Wob = Whb + 512 * 512;                      // [15,16) MB

    cast_all_bf16<<<3584, 256, 0, stream>>>(query, enc, Ws, Wh, Wout,
                                            qb, eb, Wsb, Whb, Wob, E);
    gemm64_tanh_dual<<<512, 256, 0, stream>>>(qb, Wsb, wsq, eb, Whb, whe);
    energies_partial<<<1024, 512, 0, stream>>>(wsq, whe, v, len, E);
    softmax_ctx_fused<<<256, 512, 0, stream>>>(E, eb, len, ctx);
    out_gemm64_tanh<<<256, 256, 0, stream>>>(ctx, qb, Wob, out);
}

// Round 7
// 137.428 us; speedup vs baseline: 1.7380x; 1.0102x over previous
//
#include <hip/hip_runtime.h>
#include <hip/hip_bf16.h>

// BahdanauAttention on MI355X (gfx950). ALL float I/O is fp32.
// Internal compute uses bf16 MFMA (no fp32 MFMA on CDNA4).
// Pipeline (5 launches):
//  K0: cast fp32->bf16 for query/enc/W_s/W_h/W_out into ws
//  K1: A = tanh(query @ W_s^T), B = tanh(enc @ W_h^T)  [64x64 LDS-tiled MFMA]
//  K2: energies partials E4[hq][t][s] = sum_{h in hq} v_h*(A+B)/(1+A*B)
//      (tanh addition formula + paired-rcp; len-aware staging; direct stores,
//       no atomics; XCD-balanced grid: ttile in LOW bits)
//  K3: softmax(sum_hq E4, len) -> LDS bf16 weights; ctx = W @ enc [MFMA fused]
//  K4: out = tanh([ctx|query] @ W_out^T)  [64x64 LDS-tiled MFMA, concat-K]
// d_ws is 256 MiB (measured via harness fill) -> generous non-aliased layout.

typedef __attribute__((ext_vector_type(8))) short bf16x8;
typedef __attribute__((ext_vector_type(4))) float floatx4;

#define C2LOG2E 2.8853900817779268f   // 2*log2(e)
#define LOG2E   1.4426950408889634f
#define NEGBIG  -1e30f

__device__ __forceinline__ float fexp2(float x) { return __builtin_amdgcn_exp2f(x); }
__device__ __forceinline__ float frcp(float x)  { return __builtin_amdgcn_rcpf(x); }
__device__ __forceinline__ float ftanh(float x) {
    return 1.0f - 2.0f * frcp(1.0f + fexp2(C2LOG2E * x));
}

__device__ __forceinline__ unsigned int f2bf_bits(float f) {
    unsigned int u = __float_as_uint(f);
    return (u + 0x7fffu + ((u >> 16) & 1u)) >> 16;   // RNE (inputs finite)
}

// ---- K0: cast fp32 -> bf16. 3072 blocks x 256 thr ---------------------------
__global__ __launch_bounds__(256) void cast_all_bf16(
    const float* __restrict__ q,  const float* __restrict__ e,
    const float* __restrict__ Ws, const float* __restrict__ Wh,
    const float* __restrict__ Wo,
    unsigned short* __restrict__ qb,  unsigned short* __restrict__ eb,
    unsigned short* __restrict__ Wsb, unsigned short* __restrict__ Whb,
    unsigned short* __restrict__ Wob)
{
    int blk = blockIdx.x;
    const float* src; unsigned short* dst; int base;
    if      (blk < 1024) { src = q;  dst = qb;  base = blk; }
    else if (blk < 2048) { src = e;  dst = eb;  base = blk - 1024; }
    else if (blk < 2304) { src = Ws; dst = Wsb; base = blk - 2048; }
    else if (blk < 2560) { src = Wh; dst = Whb; base = blk - 2304; }
    else                 { src = Wo; dst = Wob; base = blk - 2560; }
    size_t i = (size_t)base * 1024 + threadIdx.x * 4;
    float4 f = *(const float4*)(src + i);
    ushort4 o;
    o.x = (unsigned short)f2bf_bits(f.x);
    o.y = (unsigned short)f2bf_bits(f.y);
    o.z = (unsigned short)f2bf_bits(f.z);
    o.w = (unsigned short)f2bf_bits(f.w);
    *(ushort4*)(dst + i) = o;
}

// ---- K1: 64x64-tile LDS GEMM, dual: C = tanh(X @ W^T), two pairs ------------
__global__ __launch_bounds__(256) void gemm64_tanh_dual(
    const unsigned short* __restrict__ X1, const unsigned short* __restrict__ W1,
    float* __restrict__ C1,
    const unsigned short* __restrict__ X2, const unsigned short* __restrict__ W2,
    float* __restrict__ C2)
{
    __shared__ unsigned short sA[64 * 72];
    __shared__ unsigned short sB[64 * 72];
    const int K = 512, N = 512;
    int blk = blockIdx.x;
    const unsigned short* X; const unsigned short* W; float* C;
    if (blk < 256) { X = X1; W = W1; C = C1; }
    else           { X = X2; W = W2; C = C2; blk -= 256; }
    int mt6 = blk >> 3, nt6 = blk & 7;
    int row0 = mt6 * 64, col0 = nt6 * 64;
    int tid = threadIdx.x, lane = tid & 63, w = tid >> 6;
    int srow = tid >> 2, sseg = (tid & 3) * 16;
    int mw = (w & 1) * 32, nw = (w >> 1) * 32;
    int r = lane & 15, kq = (lane >> 4) * 8;

    floatx4 acc00 = {0,0,0,0}, acc01 = {0,0,0,0}, acc10 = {0,0,0,0}, acc11 = {0,0,0,0};
    const unsigned short* ga = X + (size_t)(row0 + srow) * K + sseg;
    const unsigned short* gb = W + (size_t)(col0 + srow) * K + sseg;

    for (int kb = 0; kb < 8; ++kb) {
        uint4 a0 = *(const uint4*)(ga);
        uint4 a1 = *(const uint4*)(ga + 8);
        uint4 b0 = *(const uint4*)(gb);
        uint4 b1 = *(const uint4*)(gb + 8);
        ga += 64; gb += 64;
        __syncthreads();
        *(uint4*)&sA[srow * 72 + sseg]     = a0;
        *(uint4*)&sA[srow * 72 + sseg + 8] = a1;
        *(uint4*)&sB[srow * 72 + sseg]     = b0;
        *(uint4*)&sB[srow * 72 + sseg + 8] = b1;
        __syncthreads();
#pragma unroll
        for (int ks = 0; ks < 64; ks += 32) {
            bf16x8 af0 = *(const bf16x8*)&sA[(mw + r) * 72 + ks + kq];
            bf16x8 af1 = *(const bf16x8*)&sA[(mw + 16 + r) * 72 + ks + kq];
            bf16x8 bf0 = *(const bf16x8*)&sB[(nw + r) * 72 + ks + kq];
            bf16x8 bf1 = *(const bf16x8*)&sB[(nw + 16 + r) * 72 + ks + kq];
            acc00 = __builtin_amdgcn_mfma_f32_16x16x32_bf16(af0, bf0, acc00, 0, 0, 0);
            acc01 = __builtin_amdgcn_mfma_f32_16x16x32_bf16(af0, bf1, acc01, 0, 0, 0);
            acc10 = __builtin_amdgcn_mfma_f32_16x16x32_bf16(af1, bf0, acc10, 0, 0, 0);
            acc11 = __builtin_amdgcn_mfma_f32_16x16x32_bf16(af1, bf1, acc11, 0, 0, 0);
        }
    }
    int rq = (lane >> 4) * 4;
    float* cp = C + (size_t)(row0 + mw + rq) * N + col0 + nw + r;
#pragma unroll
    for (int i = 0; i < 4; ++i) {
        cp[(size_t)i * N]             = ftanh(acc00[i]);
        cp[(size_t)i * N + 16]        = ftanh(acc01[i]);
        cp[(size_t)(i + 16) * N]      = ftanh(acc10[i]);
        cp[(size_t)(i + 16) * N + 16] = ftanh(acc11[i]);
    }
}

// ---- K2: energies. 1024 blocks = (b<<7)|(hq<<5)|ttile (ttile LOW: XCD bal) --
// Wave w owns t-row (ttile*8+w); lane owns s = 64j+lane, j<jmax; h slice hq*128.
// Paired-rcp: v1n1/d1 + v2n2/d2 = (x1*d2 + x2*d1)/(d1*d2), one rcp per 2 elems.
#define HC 32
__global__ __launch_bounds__(512) void energies_partial(
    const float* __restrict__ Aq,          // 2048x512 tanh(Ws_q)
    const float* __restrict__ Bh,          // 2048x512 tanh(Wh_e)
    const float* __restrict__ Vv,          // fp32 512
    const int* __restrict__ Len,
    float* __restrict__ E4)                // fp32 [4][2048][256] partials
{
    __shared__ float sB[256][36];          // stride 36: b128-aligned hh-quads
    __shared__ float sA[8][36];
    __shared__ float sV[128];

    const int H = 512;
    int tid   = threadIdx.x;
    int lane  = tid & 63;
    int w     = tid >> 6;
    int b     = blockIdx.x >> 7;
    int hq    = (blockIdx.x >> 5) & 3;
    int ttile = blockIdx.x & 31;           // LOW bits: uniform over XCDs
    int row0g = b * 256 + ttile * 8;
    int len   = Len[b];
    int jmax  = (len + 63) >> 6;           // 1..4

    if (tid < 128) sV[tid] = Vv[hq * 128 + tid];

    float acc[4] = {0.f, 0.f, 0.f, 0.f};

    for (int hc = 0; hc < 128; hc += HC) {
        __syncthreads();
        {   // stage B chunk: only jmax*64 rows x HC (len-aware)
            int rr = tid >> 3;             // 0..63
            int cc = (tid & 7) * 4;        // 0..28
            for (int jj = 0; jj < jmax; ++jj) {
                int row = jj * 64 + rr;
                float4 f = *(const float4*)(Bh + (size_t)(b * 256 + row) * H + hq * 128 + hc + cc);
                *(float4*)&sB[row][cc] = f;
            }
        }
        if (tid < 256) {                   // stage A chunk: 8 rows x HC
            int row = tid >> 5, col = tid & 31;
            sA[row][col] = Aq[(size_t)(row0g + row) * H + hq * 128 + hc + col];
        }
        __syncthreads();

#pragma unroll
        for (int hh = 0; hh < HC; hh += 4) {
            float4 a4 = *(const float4*)&sA[w][hh];       // wave-uniform b128
            float4 v4 = *(const float4*)&sV[hc + hh];     // wave-uniform b128
#pragma unroll
            for (int j = 0; j < 4; ++j) {
                if (j < jmax) {            // uniform per-block branch
                    int s = lane + 64 * j;
                    float4 b4 = *(const float4*)&sB[s][hh];
                    float n0 = a4.x + b4.x, n1 = a4.y + b4.y;
                    float n2 = a4.z + b4.z, n3 = a4.w + b4.w;
                    float d0 = fmaf(a4.x, b4.x, 1.0f), d1 = fmaf(a4.y, b4.y, 1.0f);
                    float d2 = fmaf(a4.z, b4.z, 1.0f), d3 = fmaf(a4.w, b4.w, 1.0f);
                    float x0 = v4.x * n0, x1 = v4.y * n1;
                    float x2 = v4.z * n2, x3 = v4.w * n3;
                    float num01 = fmaf(x1, d0, x0 * d1);
                    float num23 = fmaf(x3, d2, x2 * d3);
                    acc[j] = fmaf(num01, frcp(d0 * d1), acc[j]);
                    acc[j] = fmaf(num23, frcp(d2 * d3), acc[j]);
                }
            }
        }
    }

    float* erow = E4 + ((size_t)hq * 2048 + row0g + w) * 256;
#pragma unroll
    for (int j = 0; j < 4; ++j)
        if (j < jmax) erow[64 * j + lane] = acc[j];
}

// ---- K3: fused softmax + ctx GEMM. 256 blocks = (tg<<6)|(hq<<3)|b, 512 thr --
__global__ __launch_bounds__(512) void softmax_ctx_fused(
    const float* __restrict__ E4,            // fp32 [4][2048][256] partials
    const unsigned short* __restrict__ Eb,   // bf16 8x256x512
    const int* __restrict__ Len,
    unsigned short* __restrict__ Ctx)        // bf16 2048x512
{
    __shared__ unsigned short EncT[64][264];
    __shared__ unsigned short sWb[64][264];
    int tid = threadIdx.x, lane = tid & 63, w = tid >> 6;
    int blk = blockIdx.x;
    int b = blk & 7, hq = (blk >> 3) & 7, tg = blk >> 6;
    int len = Len[b];

    {   // stage + transpose enc tile: thread (s, 32-h half)
        int s = tid >> 1, hg = (tid & 1) * 32;
        const ushort4* src = (const ushort4*)(Eb + (size_t)(b * 256 + s) * 512 + hq * 64 + hg);
#pragma unroll
        for (int k = 0; k < 8; ++k) {
            ushort4 u = src[k];
            EncT[hg + k * 4 + 0][s] = u.x;
            EncT[hg + k * 4 + 1][s] = u.y;
            EncT[hg + k * 4 + 2][s] = u.z;
            EncT[hg + k * 4 + 3][s] = u.w;
        }
    }
    // softmax: wave w owns rows w*8 .. w*8+7 of the 64-row tile
    for (int i = 0; i < 8; ++i) {
        int row = w * 8 + i;
        size_t grow = (size_t)(b * 256 + tg * 64 + row) * 256;
        float ev[4];
#pragma unroll
        for (int j = 0; j < 4; ++j) {
            int s = lane + 64 * j;
            float sum = E4[grow + s] + E4[(size_t)2048 * 256 + grow + s]
                      + E4[(size_t)2 * 2048 * 256 + grow + s]
                      + E4[(size_t)3 * 2048 * 256 + grow + s];
            ev[j] = (s < len) ? sum : NEGBIG;
        }
        float m = fmaxf(fmaxf(ev[0], ev[1]), fmaxf(ev[2], ev[3]));
#pragma unroll
        for (int o = 1; o < 64; o <<= 1) m = fmaxf(m, __shfl_xor(m, o, 64));
        float wv[4], wsum = 0.f;
#pragma unroll
        for (int j = 0; j < 4; ++j) { wv[j] = fexp2((ev[j] - m) * LOG2E); wsum += wv[j]; }
#pragma unroll
        for (int o = 1; o < 64; o <<= 1) wsum += __shfl_xor(wsum, o, 64);
        float inv = frcp(wsum);
#pragma unroll
        for (int j = 0; j < 4; ++j)
            sWb[row][lane + 64 * j] = (unsigned short)f2bf_bits(wv[j] * inv);
    }
    __syncthreads();

    int mt = w & 3, npair = w >> 2;          // wave: 16 t x 32 h (2 n-tiles)
    int t0 = mt * 16;
    int r  = lane & 15, kq = (lane >> 4) * 8;
    int n0 = npair * 32 + r;
    floatx4 acc0 = {0.f,0.f,0.f,0.f}, acc1 = {0.f,0.f,0.f,0.f};
#pragma unroll
    for (int k = 0; k < 8; ++k) {
        bf16x8 a  = *(const bf16x8*)(&sWb[t0 + r][kq + 32 * k]);
        bf16x8 b0 = *(const bf16x8*)(&EncT[n0][kq + 32 * k]);
        bf16x8 b1 = *(const bf16x8*)(&EncT[n0 + 16][kq + 32 * k]);
        acc0 = __builtin_amdgcn_mfma_f32_16x16x32_bf16(a, b0, acc0, 0, 0, 0);
        acc1 = __builtin_amdgcn_mfma_f32_16x16x32_bf16(a, b1, acc1, 0, 0, 0);
    }
    int row0 = (lane >> 4) * 4;
    unsigned short* op = Ctx + (size_t)(b * 256 + tg * 64 + t0 + row0) * 512 + hq * 64 + npair * 32 + r;
#pragma unroll
    for (int i = 0; i < 4; ++i) {
        op[i * 512]      = (unsigned short)f2bf_bits(acc0[i]);
        op[i * 512 + 16] = (unsigned short)f2bf_bits(acc1[i]);
    }
}

// ---- K4: 64x64-tile LDS GEMM, concat-K: out = tanh([ctx|q] @ Wout^T) --------
__global__ __launch_bounds__(256) void out_gemm64_tanh(
    const unsigned short* __restrict__ Ctx, const unsigned short* __restrict__ Q,
    const unsigned short* __restrict__ Wout, float* __restrict__ Out)
{
    __shared__ unsigned short sA[64 * 72];
    __shared__ unsigned short sB[64 * 72];
    const int N = 512, KW = 1024;
    int blk = blockIdx.x;
    int mt6 = blk >> 3, nt6 = blk & 7;
    int row0 = mt6 * 64, col0 = nt6 * 64;
    int tid = threadIdx.x, lane = tid & 63, w = tid >> 6;
    int srow = tid >> 2, sseg = (tid & 3) * 16;
    int mw = (w & 1) * 32, nw = (w >> 1) * 32;
    int r = lane & 15, kq = (lane >> 4) * 8;

    floatx4 acc00 = {0,0,0,0}, acc01 = {0,0,0,0}, acc10 = {0,0,0,0}, acc11 = {0,0,0,0};
    const unsigned short* gb = Wout + (size_t)(col0 + srow) * KW + sseg;

    for (int kb = 0; kb < 16; ++kb) {
        const unsigned short* asrc = (kb < 8 ? Ctx : Q);
        const unsigned short* ga = asrc + (size_t)(row0 + srow) * 512 + (kb & 7) * 64 + sseg;
        uint4 a0 = *(const uint4*)(ga);
        uint4 a1 = *(const uint4*)(ga + 8);
        uint4 b0 = *(const uint4*)(gb);
        uint4 b1 = *(const uint4*)(gb + 8);
        gb += 64;
        __syncthreads();
        *(uint4*)&sA[srow * 72 + sseg]     = a0;
        *(uint4*)&sA[srow * 72 + sseg + 8] = a1;
        *(uint4*)&sB[srow * 72 + sseg]     = b0;
        *(uint4*)&sB[srow * 72 + sseg + 8] = b1;
        __syncthreads();
#pragma unroll
        for (int ks = 0; ks < 64; ks += 32) {
            bf16x8 af0 = *(const bf16x8*)&sA[(mw + r) * 72 + ks + kq];
            bf16x8 af1 = *(const bf16x8*)&sA[(mw + 16 + r) * 72 + ks + kq];
            bf16x8 bf0 = *(const bf16x8*)&sB[(nw + r) * 72 + ks + kq];
            bf16x8 bf1 = *(const bf16x8*)&sB[(nw + 16 + r) * 72 + ks + kq];
            acc00 = __builtin_amdgcn_mfma_f32_16x16x32_bf16(af0, bf0, acc00, 0, 0, 0);
            acc01 = __builtin_amdgcn_mfma_f32_16x16x32_bf16(af0, bf1, acc01, 0, 0, 0);
            acc10 = __builtin_amdgcn_mfma_f32_16x16x32_bf16(af1, bf0, acc10, 0, 0, 0);
            acc11 = __builtin_amdgcn_mfma_f32_16x16x32_bf16(af1, bf1, acc11, 0, 0, 0);
        }
    }
    int rq = (lane >> 4) * 4;
    float* op = Out + (size_t)(row0 + mw + rq) * N + col0 + nw + r;
#pragma unroll
    for (int i = 0; i < 4; ++i) {
        op[(size_t)i * N]             = ftanh(acc00[i]);
        op[(size_t)i * N + 16]        = ftanh(acc01[i]);
        op[(size_t)(i + 16) * N]      = ftanh(acc10[i]);
        op[(size_t)(i + 16) * N + 16] = ftanh(acc11[i]);
    }
}

extern "C" void kernel_launch(void* const* d_in, const int* in_sizes, int n_in,
                              void* d_out, int out_size, void* d_ws, size_t ws_size,
                              hipStream_t stream)
{
    const float* query = (const float*)d_in[0]; // fp32 8x256x512
    const float* enc   = (const float*)d_in[1]; // fp32 8x256x512
    const int*   len   = (const int*)d_in[2];   // int32 8
    const float* Ws    = (const float*)d_in[3]; // fp32 512x512
    const float* Wh    = (const float*)d_in[4]; // fp32 512x512
    const float* v     = (const float*)d_in[5]; // fp32 512
    const float* Wout  = (const float*)d_in[6]; // fp32 512x1024
    float* out = (float*)d_out;                 // fp32 8x256x512

    // d_ws is 256 MiB; generous non-aliased layout (~26 MB used)
    float* wsq = (float*)d_ws;                                  // A: 4 MB
    float* whe = wsq + 2048 * 512;                              // B: 4 MB
    float* E4  = whe + 2048 * 512;                              // 8 MB [4][2048][256]
    unsigned short* qb  = (unsigned short*)(E4 + 4 * 2048 * 256); // 2 MB
    unsigned short* eb  = qb + 2048 * 512;                      // 2 MB
    unsigned short* Wsb = eb + 2048 * 512;                      // 0.5 MB
    unsigned short* Whb = Wsb + 512 * 512;                      // 0.5 MB
    unsigned short* Wob = Whb + 512 * 512;                      // 1 MB
    unsigned short* ctx = Wob + 512 * 1024;                     // 2 MB

    cast_all_bf16<<<3072, 256, 0, stream>>>(query, enc, Ws, Wh, Wout,
                                            qb, eb, Wsb, Whb, Wob);
    gemm64_tanh_dual<<<512, 256, 0, stream>>>(qb, Wsb, wsq, eb, Whb, whe);
    energies_partial<<<1024, 512, 0, stream>>>(wsq, whe, v, len, E4);
    softmax_ctx_fused<<<256, 512, 0, stream>>>(E4, eb, len, ctx);
    out_gemm64_tanh<<<256, 256, 0, stream>>>(ctx, qb, Wob, out);
}

// Round 8
// 135.398 us; speedup vs baseline: 1.7640x; 1.0150x over previous
//
#include <hip/hip_runtime.h>
#include <hip/hip_bf16.h>

// BahdanauAttention on MI355X (gfx950). ALL float I/O is fp32.
// Internal compute uses bf16 MFMA (no fp32 MFMA on CDNA4).
// Pipeline (5 launches):
//  K0: cast fp32->bf16 for query/enc/W_s/W_h/W_out into ws
//  K1: A = tanh(query @ W_s^T), B = tanh(enc @ W_h^T)  [32x64 LDS-tiled MFMA]
//  K2: energies partials E8[hq][t][s] = sum_{h in 64-slice} v_h*(A+B)/(1+A*B)
//      (tanh addition formula + paired-rcp; len-aware staging; direct stores;
//       XCD-balanced grid: ttile LOW bits; hq split 8 for queue depth)
//  K3: softmax(sum_hq E8, len) -> LDS bf16 weights; ctx = W @ enc [MFMA fused]
//  K4: out = tanh([ctx|query] @ W_out^T)  [32x64 LDS-tiled MFMA, concat-K]
// d_ws is 256 MiB; harness 0xAA fill (~43 us) is a fixed serialized cost.

typedef __attribute__((ext_vector_type(8))) short bf16x8;
typedef __attribute__((ext_vector_type(4))) float floatx4;

#define C2LOG2E 2.8853900817779268f   // 2*log2(e)
#define LOG2E   1.4426950408889634f
#define NEGBIG  -1e30f

__device__ __forceinline__ float fexp2(float x) { return __builtin_amdgcn_exp2f(x); }
__device__ __forceinline__ float frcp(float x)  { return __builtin_amdgcn_rcpf(x); }
__device__ __forceinline__ float ftanh(float x) {
    return 1.0f - 2.0f * frcp(1.0f + fexp2(C2LOG2E * x));
}

__device__ __forceinline__ unsigned int f2bf_bits(float f) {
    unsigned int u = __float_as_uint(f);
    return (u + 0x7fffu + ((u >> 16) & 1u)) >> 16;   // RNE (inputs finite)
}

// ---- K0: cast fp32 -> bf16. 3072 blocks x 256 thr ---------------------------
__global__ __launch_bounds__(256) void cast_all_bf16(
    const float* __restrict__ q,  const float* __restrict__ e,
    const float* __restrict__ Ws, const float* __restrict__ Wh,
    const float* __restrict__ Wo,
    unsigned short* __restrict__ qb,  unsigned short* __restrict__ eb,
    unsigned short* __restrict__ Wsb, unsigned short* __restrict__ Whb,
    unsigned short* __restrict__ Wob)
{
    int blk = blockIdx.x;
    const float* src; unsigned short* dst; int base;
    if      (blk < 1024) { src = q;  dst = qb;  base = blk; }
    else if (blk < 2048) { src = e;  dst = eb;  base = blk - 1024; }
    else if (blk < 2304) { src = Ws; dst = Wsb; base = blk - 2048; }
    else if (blk < 2560) { src = Wh; dst = Whb; base = blk - 2304; }
    else                 { src = Wo; dst = Wob; base = blk - 2560; }
    size_t i = (size_t)base * 1024 + threadIdx.x * 4;
    float4 f = *(const float4*)(src + i);
    ushort4 o;
    o.x = (unsigned short)f2bf_bits(f.x);
    o.y = (unsigned short)f2bf_bits(f.y);
    o.z = (unsigned short)f2bf_bits(f.z);
    o.w = (unsigned short)f2bf_bits(f.w);
    *(ushort4*)(dst + i) = o;
}

// ---- K1: 32x64-tile LDS GEMM, dual: C = tanh(X @ W^T) -----------------------
// X: 2048x512 bf16, W: 512x512 bf16, C fp32. 1024 blocks = pair*512 + mt*8 + nt.
// 256 thr = 4 waves: wave (w&1) -> m-half (16 rows), (w>>1) -> n-half (32 cols).
__global__ __launch_bounds__(256) void gemm32x64_tanh_dual(
    const unsigned short* __restrict__ X1, const unsigned short* __restrict__ W1,
    float* __restrict__ C1,
    const unsigned short* __restrict__ X2, const unsigned short* __restrict__ W2,
    float* __restrict__ C2)
{
    __shared__ unsigned short sA[32 * 72];
    __shared__ unsigned short sB[64 * 72];
    const int K = 512, N = 512;
    int blk = blockIdx.x;
    const unsigned short* X; const unsigned short* W; float* C;
    if (blk < 512) { X = X1; W = W1; C = C1; }
    else           { X = X2; W = W2; C = C2; blk -= 512; }
    int mt = blk >> 3, nt = blk & 7;
    int row0 = mt * 32, col0 = nt * 64;
    int tid = threadIdx.x, lane = tid & 63, w = tid >> 6;
    int srA = tid >> 3, scA = (tid & 7) * 8;     // 32 x 64 staging, 8 bf16/thr
    int srB = tid >> 2, scB = (tid & 3) * 16;    // 64 x 64 staging, 16 bf16/thr
    int mw = (w & 1) * 16, nw = (w >> 1) * 32;
    int r = lane & 15, kq = (lane >> 4) * 8;

    floatx4 acc0 = {0,0,0,0}, acc1 = {0,0,0,0};
    const unsigned short* ga = X + (size_t)(row0 + srA) * K + scA;
    const unsigned short* gb = W + (size_t)(col0 + srB) * K + scB;

    for (int kb = 0; kb < 8; ++kb) {
        uint4 a0 = *(const uint4*)(ga);
        uint4 b0 = *(const uint4*)(gb);
        uint4 b1 = *(const uint4*)(gb + 8);
        ga += 64; gb += 64;
        __syncthreads();
        *(uint4*)&sA[srA * 72 + scA]     = a0;
        *(uint4*)&sB[srB * 72 + scB]     = b0;
        *(uint4*)&sB[srB * 72 + scB + 8] = b1;
        __syncthreads();
#pragma unroll
        for (int ks = 0; ks < 64; ks += 32) {
            bf16x8 af  = *(const bf16x8*)&sA[(mw + r) * 72 + ks + kq];
            bf16x8 bf0 = *(const bf16x8*)&sB[(nw + r) * 72 + ks + kq];
            bf16x8 bf1 = *(const bf16x8*)&sB[(nw + 16 + r) * 72 + ks + kq];
            acc0 = __builtin_amdgcn_mfma_f32_16x16x32_bf16(af, bf0, acc0, 0, 0, 0);
            acc1 = __builtin_amdgcn_mfma_f32_16x16x32_bf16(af, bf1, acc1, 0, 0, 0);
        }
    }
    int rq = (lane >> 4) * 4;
    float* cp = C + (size_t)(row0 + mw + rq) * N + col0 + nw + r;
#pragma unroll
    for (int i = 0; i < 4; ++i) {
        cp[(size_t)i * N]      = ftanh(acc0[i]);
        cp[(size_t)i * N + 16] = ftanh(acc1[i]);
    }
}

// ---- K2: energies. 2048 blocks = (b<<8)|(hq<<5)|ttile (ttile LOW: XCD bal) --
// hq: 8 slices of 64 h. Wave w owns t-row (ttile*8+w); lane owns s=64j+lane.
// Paired-rcp: v1n1/d1 + v2n2/d2 = (x1*d2 + x2*d1)/(d1*d2), one rcp per 2 elems.
#define HC 32
__global__ __launch_bounds__(512) void energies_partial(
    const float* __restrict__ Aq,          // 2048x512 tanh(Ws_q)
    const float* __restrict__ Bh,          // 2048x512 tanh(Wh_e)
    const float* __restrict__ Vv,          // fp32 512
    const int* __restrict__ Len,
    float* __restrict__ E8)                // fp32 [8][2048][256] partials
{
    __shared__ float sB[256][36];          // stride 36: b128-aligned hh-quads
    __shared__ float sA[8][36];
    __shared__ float sV[64];

    const int H = 512;
    int tid   = threadIdx.x;
    int lane  = tid & 63;
    int w     = tid >> 6;
    int b     = blockIdx.x >> 8;
    int hq    = (blockIdx.x >> 5) & 7;     // 64-h slice
    int ttile = blockIdx.x & 31;           // LOW bits: uniform over XCDs
    int row0g = b * 256 + ttile * 8;
    int len   = Len[b];
    int jmax  = (len + 63) >> 6;           // 1..4

    if (tid < 64) sV[tid] = Vv[hq * 64 + tid];

    float acc[4] = {0.f, 0.f, 0.f, 0.f};

    for (int hc = 0; hc < 64; hc += HC) {
        __syncthreads();
        {   // stage B chunk: only jmax*64 rows x HC (len-aware)
            int rr = tid >> 3;             // 0..63
            int cc = (tid & 7) * 4;        // 0..28
            for (int jj = 0; jj < jmax; ++jj) {
                int row = jj * 64 + rr;
                float4 f = *(const float4*)(Bh + (size_t)(b * 256 + row) * H + hq * 64 + hc + cc);
                *(float4*)&sB[row][cc] = f;
            }
        }
        if (tid < 256) {                   // stage A chunk: 8 rows x HC
            int row = tid >> 5, col = tid & 31;
            sA[row][col] = Aq[(size_t)(row0g + row) * H + hq * 64 + hc + col];
        }
        __syncthreads();

#pragma unroll
        for (int hh = 0; hh < HC; hh += 4) {
            float4 a4 = *(const float4*)&sA[w][hh];       // wave-uniform b128
            float4 v4 = *(const float4*)&sV[hc + hh];     // wave-uniform b128
#pragma unroll
            for (int j = 0; j < 4; ++j) {
                if (j < jmax) {            // uniform per-block branch
                    int s = lane + 64 * j;
                    float4 b4 = *(const float4*)&sB[s][hh];
                    float n0 = a4.x + b4.x, n1 = a4.y + b4.y;
                    float n2 = a4.z + b4.z, n3 = a4.w + b4.w;
                    float d0 = fmaf(a4.x, b4.x, 1.0f), d1 = fmaf(a4.y, b4.y, 1.0f);
                    float d2 = fmaf(a4.z, b4.z, 1.0f), d3 = fmaf(a4.w, b4.w, 1.0f);
                    float x0 = v4.x * n0, x1 = v4.y * n1;
                    float x2 = v4.z * n2, x3 = v4.w * n3;
                    float num01 = fmaf(x1, d0, x0 * d1);
                    float num23 = fmaf(x3, d2, x2 * d3);
                    acc[j] = fmaf(num01, frcp(d0 * d1), acc[j]);
                    acc[j] = fmaf(num23, frcp(d2 * d3), acc[j]);
                }
            }
        }
    }

    float* erow = E8 + ((size_t)hq * 2048 + row0g + w) * 256;
#pragma unroll
    for (int j = 0; j < 4; ++j)
        if (j < jmax) erow[64 * j + lane] = acc[j];
}

// ---- K3: fused softmax + ctx GEMM. 256 blocks = (tg<<6)|(hq<<3)|b, 512 thr --
__global__ __launch_bounds__(512) void softmax_ctx_fused(
    const float* __restrict__ E8,            // fp32 [8][2048][256] partials
    const unsigned short* __restrict__ Eb,   // bf16 8x256x512
    const int* __restrict__ Len,
    unsigned short* __restrict__ Ctx)        // bf16 2048x512
{
    __shared__ unsigned short EncT[64][264];
    __shared__ unsigned short sWb[64][264];
    int tid = threadIdx.x, lane = tid & 63, w = tid >> 6;
    int blk = blockIdx.x;
    int b = blk & 7, hq = (blk >> 3) & 7, tg = blk >> 6;
    int len = Len[b];

    {   // stage + transpose enc tile: thread (s, 32-h half)
        int s = tid >> 1, hg = (tid & 1) * 32;
        const ushort4* src = (const ushort4*)(Eb + (size_t)(b * 256 + s) * 512 + hq * 64 + hg);
#pragma unroll
        for (int k = 0; k < 8; ++k) {
            ushort4 u = src[k];
            EncT[hg + k * 4 + 0][s] = u.x;
            EncT[hg + k * 4 + 1][s] = u.y;
            EncT[hg + k * 4 + 2][s] = u.z;
            EncT[hg + k * 4 + 3][s] = u.w;
        }
    }
    // softmax: wave w owns rows w*8 .. w*8+7 of the 64-row tile
    const size_t SL = (size_t)2048 * 256;
    for (int i = 0; i < 8; ++i) {
        int row = w * 8 + i;
        size_t grow = (size_t)(b * 256 + tg * 64 + row) * 256;
        float ev[4];
#pragma unroll
        for (int j = 0; j < 4; ++j) {
            int s = lane + 64 * j;
            float sum = (E8[grow + s]          + E8[SL + grow + s])
                      + (E8[2 * SL + grow + s] + E8[3 * SL + grow + s]);
            sum += (E8[4 * SL + grow + s] + E8[5 * SL + grow + s])
                 + (E8[6 * SL + grow + s] + E8[7 * SL + grow + s]);
            ev[j] = (s < len) ? sum : NEGBIG;
        }
        float m = fmaxf(fmaxf(ev[0], ev[1]), fmaxf(ev[2], ev[3]));
#pragma unroll
        for (int o = 1; o < 64; o <<= 1) m = fmaxf(m, __shfl_xor(m, o, 64));
        float wv[4], wsum = 0.f;
#pragma unroll
        for (int j = 0; j < 4; ++j) { wv[j] = fexp2((ev[j] - m) * LOG2E); wsum += wv[j]; }
#pragma unroll
        for (int o = 1; o < 64; o <<= 1) wsum += __shfl_xor(wsum, o, 64);
        float inv = frcp(wsum);
#pragma unroll
        for (int j = 0; j < 4; ++j)
            sWb[row][lane + 64 * j] = (unsigned short)f2bf_bits(wv[j] * inv);
    }
    __syncthreads();

    int mt = w & 3, npair = w >> 2;          // wave: 16 t x 32 h (2 n-tiles)
    int t0 = mt * 16;
    int r  = lane & 15, kq = (lane >> 4) * 8;
    int n0 = npair * 32 + r;
    floatx4 acc0 = {0.f,0.f,0.f,0.f}, acc1 = {0.f,0.f,0.f,0.f};
#pragma unroll
    for (int k = 0; k < 8; ++k) {
        bf16x8 a  = *(const bf16x8*)(&sWb[t0 + r][kq + 32 * k]);
        bf16x8 b0 = *(const bf16x8*)(&EncT[n0][kq + 32 * k]);
        bf16x8 b1 = *(const bf16x8*)(&EncT[n0 + 16][kq + 32 * k]);
        acc0 = __builtin_amdgcn_mfma_f32_16x16x32_bf16(a, b0, acc0, 0, 0, 0);
        acc1 = __builtin_amdgcn_mfma_f32_16x16x32_bf16(a, b1, acc1, 0, 0, 0);
    }
    int row0 = (lane >> 4) * 4;
    unsigned short* op = Ctx + (size_t)(b * 256 + tg * 64 + t0 + row0) * 512 + hq * 64 + npair * 32 + r;
#pragma unroll
    for (int i = 0; i < 4; ++i) {
        op[i * 512]      = (unsigned short)f2bf_bits(acc0[i]);
        op[i * 512 + 16] = (unsigned short)f2bf_bits(acc1[i]);
    }
}

// ---- K4: 32x64-tile LDS GEMM, concat-K: out = tanh([ctx|q] @ Wout^T) --------
// 512 blocks = mt*8 + nt (mt 0..63, nt 0..7). 256 thr = 4 waves.
__global__ __launch_bounds__(256) void out_gemm32x64_tanh(
    const unsigned short* __restrict__ Ctx, const unsigned short* __restrict__ Q,
    const unsigned short* __restrict__ Wout, float* __restrict__ Out)
{
    __shared__ unsigned short sA[32 * 72];
    __shared__ unsigned short sB[64 * 72];
    const int N = 512, KW = 1024;
    int blk = blockIdx.x;
    int mt = blk >> 3, nt = blk & 7;
    int row0 = mt * 32, col0 = nt * 64;
    int tid = threadIdx.x, lane = tid & 63, w = tid >> 6;
    int srA = tid >> 3, scA = (tid & 7) * 8;
    int srB = tid >> 2, scB = (tid & 3) * 16;
    int mw = (w & 1) * 16, nw = (w >> 1) * 32;
    int r = lane & 15, kq = (lane >> 4) * 8;

    floatx4 acc0 = {0,0,0,0}, acc1 = {0,0,0,0};
    const unsigned short* gb = Wout + (size_t)(col0 + srB) * KW + scB;

    for (int kb = 0; kb < 16; ++kb) {
        const unsigned short* asrc = (kb < 8 ? Ctx : Q);
        const unsigned short* ga = asrc + (size_t)(row0 + srA) * 512 + (kb & 7) * 64 + scA;
        uint4 a0 = *(const uint4*)(ga);
        uint4 b0 = *(const uint4*)(gb);
        uint4 b1 = *(const uint4*)(gb + 8);
        gb += 64;
        __syncthreads();
        *(uint4*)&sA[srA * 72 + scA]     = a0;
        *(uint4*)&sB[srB * 72 + scB]     = b0;
        *(uint4*)&sB[srB * 72 + scB + 8] = b1;
        __syncthreads();
#pragma unroll
        for (int ks = 0; ks < 64; ks += 32) {
            bf16x8 af  = *(const bf16x8*)&sA[(mw + r) * 72 + ks + kq];
            bf16x8 bf0 = *(const bf16x8*)&sB[(nw + r) * 72 + ks + kq];
            bf16x8 bf1 = *(const bf16x8*)&sB[(nw + 16 + r) * 72 + ks + kq];
            acc0 = __builtin_amdgcn_mfma_f32_16x16x32_bf16(af, bf0, acc0, 0, 0, 0);
            acc1 = __builtin_amdgcn_mfma_f32_16x16x32_bf16(af, bf1, acc1, 0, 0, 0);
        }
    }
    int rq = (lane >> 4) * 4;
    float* op = Out + (size_t)(row0 + mw + rq) * N + col0 + nw + r;
#pragma unroll
    for (int i = 0; i < 4; ++i) {
        op[(size_t)i * N]      = ftanh(acc0[i]);
        op[(size_t)i * N + 16] = ftanh(acc1[i]);
    }
}

extern "C" void kernel_launch(void* const* d_in, const int* in_sizes, int n_in,
                              void* d_out, int out_size, void* d_ws, size_t ws_size,
                              hipStream_t stream)
{
    const float* query = (const float*)d_in[0]; // fp32 8x256x512
    const float* enc   = (const float*)d_in[1]; // fp32 8x256x512
    const int*   len   = (const int*)d_in[2];   // int32 8
    const float* Ws    = (const float*)d_in[3]; // fp32 512x512
    const float* Wh    = (const float*)d_in[4]; // fp32 512x512
    const float* v     = (const float*)d_in[5]; // fp32 512
    const float* Wout  = (const float*)d_in[6]; // fp32 512x1024
    float* out = (float*)d_out;                 // fp32 8x256x512

    // d_ws is 256 MiB; generous non-aliased layout (~34 MB used)
    float* wsq = (float*)d_ws;                                    // A: 4 MB
    float* whe = wsq + 2048 * 512;                                // B: 4 MB
    float* E8  = whe + 2048 * 512;                                // 16 MB [8][2048][256]
    unsigned short* qb  = (unsigned short*)(E8 + 8 * 2048 * 256); // 2 MB
    unsigned short* eb  = qb + 2048 * 512;                        // 2 MB
    unsigned short* Wsb = eb + 2048 * 512;                        // 0.5 MB
    unsigned short* Whb = Wsb + 512 * 512;                        // 0.5 MB
    unsigned short* Wob = Whb + 512 * 512;                        // 1 MB
    unsigned short* ctx = Wob + 512 * 1024;                       // 2 MB

    cast_all_bf16<<<3072, 256, 0, stream>>>(query, enc, Ws, Wh, Wout,
                                            qb, eb, Wsb, Whb, Wob);
    gemm32x64_tanh_dual<<<1024, 256, 0, stream>>>(qb, Wsb, wsq, eb, Whb, whe);
    energies_partial<<<2048, 512, 0, stream>>>(wsq, whe, v, len, E8);
    softmax_ctx_fused<<<256, 512, 0, stream>>>(E8, eb, len, ctx);
    out_gemm32x64_tanh<<<512, 256, 0, stream>>>(ctx, qb, Wob, out);
}